// Round 1
// baseline (1677.744 us; speedup 1.0000x reference)
//
#include <hip/hip_runtime.h>

#define H 64

// ---------------- zero-fill ----------------
__global__ void zero_i32(int* p, int n) {
    int i = blockIdx.x * blockDim.x + threadIdx.x;
    if (i < n) p[i] = 0;
}
__global__ void zero_f32(float* p, int n) {
    int i = blockIdx.x * blockDim.x + threadIdx.x;
    if (i < n) p[i] = 0.f;
}

// ---------------- degree / dinv ----------------
__global__ void deg_count(const int* __restrict__ dst, int E, int* __restrict__ counts) {
    int e = blockIdx.x * blockDim.x + threadIdx.x;
    if (e < E) atomicAdd(&counts[dst[e]], 1);
}
__global__ void compute_dinv(const int* __restrict__ counts, float* __restrict__ dinv, int N) {
    int i = blockIdx.x * blockDim.x + threadIdx.x;
    if (i < N) dinv[i] = rsqrtf((float)(counts[i] + 1));  // +1 self-loop, deg>=1
}

// ---------------- exclusive scan (3-phase) ----------------
__global__ void scan_phase1(const int* __restrict__ counts, int* __restrict__ rowstart,
                            int* __restrict__ blockSums, int N) {
    __shared__ int t[256];
    int tid = threadIdx.x;
    int i = blockIdx.x * 256 + tid;
    int v = (i < N) ? counts[i] : 0;
    t[tid] = v;
    __syncthreads();
    for (int off = 1; off < 256; off <<= 1) {
        int x = (tid >= off) ? t[tid - off] : 0;
        __syncthreads();
        t[tid] += x;
        __syncthreads();
    }
    if (i < N) rowstart[i] = t[tid] - v;           // exclusive within block
    if (tid == 255) blockSums[blockIdx.x] = t[255]; // block total
}
__global__ void scan_phase2(int* __restrict__ blockSums, int nb) {
    __shared__ int t[512];
    int tid = threadIdx.x;
    int v = (tid < nb) ? blockSums[tid] : 0;
    t[tid] = v;
    __syncthreads();
    for (int off = 1; off < 512; off <<= 1) {
        int x = (tid >= off) ? t[tid - off] : 0;
        __syncthreads();
        t[tid] += x;
        __syncthreads();
    }
    if (tid < nb) blockSums[tid] = t[tid] - v;     // exclusive
}
__global__ void scan_phase3(int* __restrict__ rowstart, int* __restrict__ cursor,
                            const int* __restrict__ blockSums, int N) {
    int i = blockIdx.x * 256 + threadIdx.x;
    if (i < N) {
        int r = rowstart[i] + blockSums[blockIdx.x];
        rowstart[i] = r;
        cursor[i] = r;
    }
}

// ---------------- CSR scatter ----------------
__global__ void scatter_edges(const int* __restrict__ src, const int* __restrict__ dst, int E,
                              int* __restrict__ cursor, int* __restrict__ col) {
    int e = blockIdx.x * blockDim.x + threadIdx.x;
    if (e < E) {
        int p = atomicAdd(&cursor[dst[e]], 1);
        col[p] = src[e];
    }
}
// after scatter, cursor[i] == row end of node i

// ---------------- pool counts ----------------
__global__ void pool_count(const int* __restrict__ batch, float* __restrict__ cnt, int N) {
    int i = blockIdx.x * blockDim.x + threadIdx.x;
    if (i < N) atomicAdd(&cnt[batch[i]], 1.f);
}

// ---------------- linear: N x 9 @ 9 x 64 ----------------
__global__ void lin_in(const float* __restrict__ x, const float* __restrict__ W,
                       float* __restrict__ out, int N) {
    __shared__ float Ws[9 * H];
    __shared__ float xs[4 * 9];
    int tid = threadIdx.x;
    for (int idx = tid; idx < 9 * H; idx += 256) Ws[idx] = W[idx];
    int node0 = blockIdx.x * 4;
    for (int idx = tid; idx < 4 * 9; idx += 256) {
        int nl = idx / 9, k = idx % 9;
        int n = node0 + nl;
        xs[idx] = (n < N) ? x[n * 9 + k] : 0.f;
    }
    __syncthreads();
    int nl = tid >> 6, f = tid & 63;
    int n = node0 + nl;
    float acc = 0.f;
#pragma unroll
    for (int k = 0; k < 9; ++k) acc += xs[nl * 9 + k] * Ws[k * H + f];
    if (n < N) out[n * H + f] = acc;
}

// ---------------- linear: N x 64 @ 64 x 64 (16 nodes/block) ----------------
__global__ void lin_h(const float* __restrict__ h, const float* __restrict__ W,
                      float* __restrict__ out, int N) {
    __shared__ float Ws[H * H];     // 16 KB
    __shared__ float hs[16 * H];    // 4 KB
    int tid = threadIdx.x;
    int node0 = blockIdx.x * 16;
    for (int idx = tid; idx < H * H; idx += 256) Ws[idx] = W[idx];
    for (int idx = tid; idx < 16 * H; idx += 256) {
        int n = node0 + (idx >> 6);
        hs[idx] = (n < N) ? h[n * H + (idx & 63)] : 0.f;
    }
    __syncthreads();
    int nlb = tid >> 6, f = tid & 63;
    float a0 = 0.f, a1 = 0.f, a2 = 0.f, a3 = 0.f;
#pragma unroll 8
    for (int k = 0; k < H; ++k) {
        float w = Ws[k * H + f];
        a0 += hs[(nlb) * H + k] * w;
        a1 += hs[(nlb + 4) * H + k] * w;
        a2 += hs[(nlb + 8) * H + k] * w;
        a3 += hs[(nlb + 12) * H + k] * w;
    }
    int n;
    n = node0 + nlb;      if (n < N) out[n * H + f] = a0;
    n = node0 + nlb + 4;  if (n < N) out[n * H + f] = a1;
    n = node0 + nlb + 8;  if (n < N) out[n * H + f] = a2;
    n = node0 + nlb + 12; if (n < N) out[n * H + f] = a3;
}

// ---------------- aggregate: one wave per node, lane = feature ----------------
template <bool POOL>
__global__ void aggregate(const float* __restrict__ hw, const float* __restrict__ dinv,
                          const int* __restrict__ rowstart, const int* __restrict__ rowend,
                          const int* __restrict__ col, const float* __restrict__ bias,
                          float* __restrict__ out, const int* __restrict__ batch,
                          float* __restrict__ pool, int N) {
    int gtid = blockIdx.x * blockDim.x + threadIdx.x;
    int i = gtid >> 6;       // node = wave
    int f = threadIdx.x & 63;
    if (i >= N) return;
    float di = dinv[i];
    float acc = di * hw[i * H + f];  // self-loop term (x di again at the end)
    int s = rowstart[i], e = rowend[i];
    for (int p = s; p < e; ++p) {
        int sidx = col[p];
        acc += dinv[sidx] * hw[sidx * H + f];
    }
    float val = fmaxf(bias[f] + di * acc, 0.f);
    if (POOL) {
        atomicAdd(&pool[batch[i] * H + f], val);
    } else {
        out[i * H + f] = val;
    }
}

// ---------------- final MLP: one thread per graph ----------------
__global__ void mlp(const float* __restrict__ pool, const float* __restrict__ cnt,
                    const float* __restrict__ u,
                    const float* __restrict__ A1, const float* __restrict__ c1,
                    const float* __restrict__ A2, const float* __restrict__ c2,
                    const float* __restrict__ A3, const float* __restrict__ c3,
                    const float* __restrict__ A4, const float* __restrict__ c4,
                    const float* __restrict__ A5, const float* __restrict__ c5,
                    float* __restrict__ out, int G) {
    int g = blockIdx.x * blockDim.x + threadIdx.x;
    if (g >= G) return;
    float z[68];
    float inv = 1.f / fmaxf(cnt[g], 1.f);
#pragma unroll
    for (int k = 0; k < H; ++k) z[k] = pool[g * H + k] * inv;
#pragma unroll
    for (int k = 0; k < 4; ++k) z[H + k] = u[g * 4 + k];

    float z1[50];
    for (int o = 0; o < 50; ++o) {
        float a = c1[o];
        for (int k = 0; k < 68; ++k) a += z[k] * A1[k * 50 + o];
        z1[o] = fmaxf(a, 0.f);
    }
    float z2[30];
    for (int o = 0; o < 30; ++o) {
        float a = c2[o];
        for (int k = 0; k < 50; ++k) a += z1[k] * A2[k * 30 + o];
        z2[o] = fmaxf(a, 0.f);
    }
    float z3[20];
    for (int o = 0; o < 20; ++o) {
        float a = c3[o];
        for (int k = 0; k < 30; ++k) a += z2[k] * A3[k * 20 + o];
        z3[o] = fmaxf(a, 0.f);
    }
    float z4[5];
    for (int o = 0; o < 5; ++o) {
        float a = c4[o];
        for (int k = 0; k < 20; ++k) a += z3[k] * A4[k * 5 + o];
        z4[o] = fmaxf(a, 0.f);
    }
    float a = c5[0];
    for (int k = 0; k < 5; ++k) a += z4[k] * A5[k];
    out[g] = fmaxf(a, 0.f);
}

extern "C" void kernel_launch(void* const* d_in, const int* in_sizes, int n_in,
                              void* d_out, int out_size, void* d_ws, size_t ws_size,
                              hipStream_t stream) {
    const float* x     = (const float*)d_in[0];
    const int*   edge  = (const int*)d_in[1];
    const int*   batch = (const int*)d_in[2];
    const float* u     = (const float*)d_in[3];
    const float* W1 = (const float*)d_in[4];  const float* b1 = (const float*)d_in[5];
    const float* W2 = (const float*)d_in[6];  const float* b2 = (const float*)d_in[7];
    const float* W3 = (const float*)d_in[8];  const float* b3 = (const float*)d_in[9];
    const float* A1 = (const float*)d_in[10]; const float* c1 = (const float*)d_in[11];
    const float* A2 = (const float*)d_in[12]; const float* c2 = (const float*)d_in[13];
    const float* A3 = (const float*)d_in[14]; const float* c3 = (const float*)d_in[15];
    const float* A4 = (const float*)d_in[16]; const float* c4 = (const float*)d_in[17];
    const float* A5 = (const float*)d_in[18]; const float* c5 = (const float*)d_in[19];

    const int N = in_sizes[2];          // 100000
    const int E = in_sizes[1] / 2;      // 3200000
    const int G = in_sizes[3] / 4;      // 256
    const int* src = edge;
    const int* dst = edge + E;

    // ---- workspace layout ----
    char* ws = (char*)d_ws;
    size_t off = 0;
    auto alloc = [&](size_t bytes) -> void* {
        void* p = ws + off;
        off = (off + bytes + 255) & ~(size_t)255;
        return p;
    };
    int*   counts    = (int*)alloc((size_t)N * 4);
    int*   rowstart  = (int*)alloc((size_t)N * 4);
    int*   cursor    = (int*)alloc((size_t)N * 4);
    int*   col       = (int*)alloc((size_t)E * 4);
    float* dinv      = (float*)alloc((size_t)N * 4);
    float* hw        = (float*)alloc((size_t)N * H * 4);
    float* h         = (float*)alloc((size_t)N * H * 4);
    float* pool      = (float*)alloc((size_t)G * H * 4);
    float* cnt       = (float*)alloc((size_t)G * 4);
    int*   blockSums = (int*)alloc(512 * 4);

    const int nbN   = (N + 255) / 256;   // 391
    const int nbE   = (E + 255) / 256;   // 12500
    const int nbAgg = (N + 3) / 4;       // 25000 (4 waves/block, wave per node)

    // ---- zero state that is accumulated into ----
    zero_i32<<<nbN, 256, 0, stream>>>(counts, N);
    zero_f32<<<(G * H + 255) / 256, 256, 0, stream>>>(pool, G * H);
    zero_f32<<<1, 256, 0, stream>>>(cnt, G);

    // ---- degree + dinv ----
    deg_count<<<nbE, 256, 0, stream>>>(dst, E, counts);
    pool_count<<<nbN, 256, 0, stream>>>(batch, cnt, N);
    compute_dinv<<<nbN, 256, 0, stream>>>(counts, dinv, N);

    // ---- CSR build (dst-indexed) ----
    scan_phase1<<<nbN, 256, 0, stream>>>(counts, rowstart, blockSums, N);
    scan_phase2<<<1, 512, 0, stream>>>(blockSums, nbN);
    scan_phase3<<<nbN, 256, 0, stream>>>(rowstart, cursor, blockSums, N);
    scatter_edges<<<nbE, 256, 0, stream>>>(src, dst, E, cursor, col);
    // cursor now holds row-end offsets

    // ---- conv1 ----
    lin_in<<<(N + 3) / 4, 256, 0, stream>>>(x, W1, hw, N);
    aggregate<false><<<nbAgg, 256, 0, stream>>>(hw, dinv, rowstart, cursor, col, b1,
                                                h, batch, pool, N);
    // ---- conv2 ----
    lin_h<<<(N + 15) / 16, 256, 0, stream>>>(h, W2, hw, N);
    aggregate<false><<<nbAgg, 256, 0, stream>>>(hw, dinv, rowstart, cursor, col, b2,
                                                h, batch, pool, N);
    // ---- conv3 (fused pooling accumulate) ----
    lin_h<<<(N + 15) / 16, 256, 0, stream>>>(h, W3, hw, N);
    aggregate<true><<<nbAgg, 256, 0, stream>>>(hw, dinv, rowstart, cursor, col, b3,
                                               h, batch, pool, N);

    // ---- final MLP over 256 graphs ----
    mlp<<<1, 256, 0, stream>>>(pool, cnt, u, A1, c1, A2, c2, A3, c3, A4, c4, A5, c5,
                               (float*)d_out, G);
}

// Round 2
// 1194.233 us; speedup vs baseline: 1.4049x; 1.4049x over previous
//
#include <hip/hip_runtime.h>

#define H 64

// ---------------- zero-fill ----------------
__global__ void zero_i32(int* p, int n) {
    int i = blockIdx.x * blockDim.x + threadIdx.x;
    if (i < n) p[i] = 0;
}
__global__ void zero_f32(float* p, int n) {
    int i = blockIdx.x * blockDim.x + threadIdx.x;
    if (i < n) p[i] = 0.f;
}

// ---------------- degree / dinv ----------------
__global__ void deg_count(const int* __restrict__ dst, int E, int* __restrict__ counts) {
    int e = blockIdx.x * blockDim.x + threadIdx.x;
    if (e < E) atomicAdd(&counts[dst[e]], 1);
}
__global__ void compute_dinv(const int* __restrict__ counts, float* __restrict__ dinv, int N) {
    int i = blockIdx.x * blockDim.x + threadIdx.x;
    if (i < N) dinv[i] = rsqrtf((float)(counts[i] + 1));  // +1 self-loop, deg>=1
}

// ---------------- exclusive scan (3-phase) ----------------
__global__ void scan_phase1(const int* __restrict__ counts, int* __restrict__ rowstart,
                            int* __restrict__ blockSums, int N) {
    __shared__ int t[256];
    int tid = threadIdx.x;
    int i = blockIdx.x * 256 + tid;
    int v = (i < N) ? counts[i] : 0;
    t[tid] = v;
    __syncthreads();
    for (int off = 1; off < 256; off <<= 1) {
        int x = (tid >= off) ? t[tid - off] : 0;
        __syncthreads();
        t[tid] += x;
        __syncthreads();
    }
    if (i < N) rowstart[i] = t[tid] - v;           // exclusive within block
    if (tid == 255) blockSums[blockIdx.x] = t[255]; // block total
}
__global__ void scan_phase2(int* __restrict__ blockSums, int nb) {
    __shared__ int t[512];
    int tid = threadIdx.x;
    int v = (tid < nb) ? blockSums[tid] : 0;
    t[tid] = v;
    __syncthreads();
    for (int off = 1; off < 512; off <<= 1) {
        int x = (tid >= off) ? t[tid - off] : 0;
        __syncthreads();
        t[tid] += x;
        __syncthreads();
    }
    if (tid < nb) blockSums[tid] = t[tid] - v;     // exclusive
}
__global__ void scan_phase3(int* __restrict__ rowstart, int* __restrict__ cursor,
                            const int* __restrict__ blockSums, int N) {
    int i = blockIdx.x * 256 + threadIdx.x;
    if (i < N) {
        int r = rowstart[i] + blockSums[blockIdx.x];
        rowstart[i] = r;
        cursor[i] = r;
    }
}

// ---------------- CSR scatter ----------------
__global__ void scatter_edges(const int* __restrict__ src, const int* __restrict__ dst, int E,
                              int* __restrict__ cursor, int* __restrict__ col) {
    int e = blockIdx.x * blockDim.x + threadIdx.x;
    if (e < E) {
        int p = atomicAdd(&cursor[dst[e]], 1);
        col[p] = src[e];
    }
}
// after scatter, cursor[i] == row end of node i

// ---------------- per-edge source norm (built once, reused by 3 convs) ----------------
__global__ void build_dnorm(const int* __restrict__ col, const float* __restrict__ dinv,
                            float* __restrict__ dnorm, int E) {
    int p = blockIdx.x * blockDim.x + threadIdx.x;
    if (p < E) dnorm[p] = dinv[col[p]];
}

// ---------------- pool counts ----------------
__global__ void pool_count(const int* __restrict__ batch, float* __restrict__ cnt, int N) {
    int i = blockIdx.x * blockDim.x + threadIdx.x;
    if (i < N) atomicAdd(&cnt[batch[i]], 1.f);
}

// ---------------- linear: N x 9 @ 9 x 64 ----------------
__global__ void lin_in(const float* __restrict__ x, const float* __restrict__ W,
                       float* __restrict__ out, int N) {
    __shared__ float Ws[9 * H];
    __shared__ float xs[4 * 9];
    int tid = threadIdx.x;
    for (int idx = tid; idx < 9 * H; idx += 256) Ws[idx] = W[idx];
    int node0 = blockIdx.x * 4;
    for (int idx = tid; idx < 4 * 9; idx += 256) {
        int nl = idx / 9, k = idx % 9;
        int n = node0 + nl;
        xs[idx] = (n < N) ? x[n * 9 + k] : 0.f;
    }
    __syncthreads();
    int nl = tid >> 6, f = tid & 63;
    int n = node0 + nl;
    float acc = 0.f;
#pragma unroll
    for (int k = 0; k < 9; ++k) acc += xs[nl * 9 + k] * Ws[k * H + f];
    if (n < N) out[n * H + f] = acc;
}

// ---------------- linear: N x 64 @ 64 x 64 (16 nodes/block) ----------------
__global__ void lin_h(const float* __restrict__ h, const float* __restrict__ W,
                      float* __restrict__ out, int N) {
    __shared__ float Ws[H * H];     // 16 KB
    __shared__ float hs[16 * H];    // 4 KB
    int tid = threadIdx.x;
    int node0 = blockIdx.x * 16;
    for (int idx = tid; idx < H * H; idx += 256) Ws[idx] = W[idx];
    for (int idx = tid; idx < 16 * H; idx += 256) {
        int n = node0 + (idx >> 6);
        hs[idx] = (n < N) ? h[n * H + (idx & 63)] : 0.f;
    }
    __syncthreads();
    int nlb = tid >> 6, f = tid & 63;
    float a0 = 0.f, a1 = 0.f, a2 = 0.f, a3 = 0.f;
#pragma unroll 8
    for (int k = 0; k < H; ++k) {
        float w = Ws[k * H + f];
        a0 += hs[(nlb) * H + k] * w;
        a1 += hs[(nlb + 4) * H + k] * w;
        a2 += hs[(nlb + 8) * H + k] * w;
        a3 += hs[(nlb + 12) * H + k] * w;
    }
    int n;
    n = node0 + nlb;      if (n < N) out[n * H + f] = a0;
    n = node0 + nlb + 4;  if (n < N) out[n * H + f] = a1;
    n = node0 + nlb + 8;  if (n < N) out[n * H + f] = a2;
    n = node0 + nlb + 12; if (n < N) out[n * H + f] = a3;
}

// ---------------- aggregate: one wave per node, lane = feature ----------------
// Chunked col/dnorm loads (coalesced, lane=edge) + shfl broadcast + 4-deep
// unroll so 4 independent 256B row gathers are in flight per wave.
template <bool POOL>
__global__ void aggregate(const float* __restrict__ hw, const float* __restrict__ dinv,
                          const int* __restrict__ rowstart, const int* __restrict__ rowend,
                          const int* __restrict__ col, const float* __restrict__ dnorm,
                          const float* __restrict__ bias,
                          float* __restrict__ out, const int* __restrict__ batch,
                          float* __restrict__ pool, int N) {
    int gtid = blockIdx.x * blockDim.x + threadIdx.x;
    int i = gtid >> 6;       // node = wave
    int f = threadIdx.x & 63;
    if (i >= N) return;
    float di = dinv[i];
    float acc = di * hw[(size_t)i * H + f];  // self-loop term (x di again at the end)
    int s = rowstart[i], e = rowend[i];
    for (int base = s; base < e; base += 64) {
        int cnt = e - base;
        if (cnt > 64) cnt = 64;
        int   idx = 0;
        float dn  = 0.f;
        if (f < cnt) {
            idx = col[base + f];     // coalesced 64-wide index load
            dn  = dnorm[base + f];   // coalesced 64-wide norm load
        }
        int j = 0;
        for (; j + 4 <= cnt; j += 4) {
            int s0 = __shfl(idx, j);     int s1 = __shfl(idx, j + 1);
            int s2 = __shfl(idx, j + 2); int s3 = __shfl(idx, j + 3);
            float d0 = __shfl(dn, j);     float d1 = __shfl(dn, j + 1);
            float d2 = __shfl(dn, j + 2); float d3 = __shfl(dn, j + 3);
            float v0 = hw[(size_t)s0 * H + f];
            float v1 = hw[(size_t)s1 * H + f];
            float v2 = hw[(size_t)s2 * H + f];
            float v3 = hw[(size_t)s3 * H + f];
            acc = fmaf(d0, v0, acc);
            acc = fmaf(d1, v1, acc);
            acc = fmaf(d2, v2, acc);
            acc = fmaf(d3, v3, acc);
        }
        for (; j < cnt; ++j) {
            int   s0 = __shfl(idx, j);
            float d0 = __shfl(dn, j);
            acc = fmaf(d0, hw[(size_t)s0 * H + f], acc);
        }
    }
    float val = fmaxf(bias[f] + di * acc, 0.f);
    if (POOL) {
        atomicAdd(&pool[batch[i] * H + f], val);
    } else {
        out[(size_t)i * H + f] = val;
    }
}

// ---------------- final MLP: one thread per graph ----------------
__global__ void mlp(const float* __restrict__ pool, const float* __restrict__ cnt,
                    const float* __restrict__ u,
                    const float* __restrict__ A1, const float* __restrict__ c1,
                    const float* __restrict__ A2, const float* __restrict__ c2,
                    const float* __restrict__ A3, const float* __restrict__ c3,
                    const float* __restrict__ A4, const float* __restrict__ c4,
                    const float* __restrict__ A5, const float* __restrict__ c5,
                    float* __restrict__ out, int G) {
    int g = blockIdx.x * blockDim.x + threadIdx.x;
    if (g >= G) return;
    float z[68];
    float inv = 1.f / fmaxf(cnt[g], 1.f);
#pragma unroll
    for (int k = 0; k < H; ++k) z[k] = pool[g * H + k] * inv;
#pragma unroll
    for (int k = 0; k < 4; ++k) z[H + k] = u[g * 4 + k];

    float z1[50];
    for (int o = 0; o < 50; ++o) {
        float a = c1[o];
        for (int k = 0; k < 68; ++k) a += z[k] * A1[k * 50 + o];
        z1[o] = fmaxf(a, 0.f);
    }
    float z2[30];
    for (int o = 0; o < 30; ++o) {
        float a = c2[o];
        for (int k = 0; k < 50; ++k) a += z1[k] * A2[k * 30 + o];
        z2[o] = fmaxf(a, 0.f);
    }
    float z3[20];
    for (int o = 0; o < 20; ++o) {
        float a = c3[o];
        for (int k = 0; k < 30; ++k) a += z2[k] * A3[k * 20 + o];
        z3[o] = fmaxf(a, 0.f);
    }
    float z4[5];
    for (int o = 0; o < 5; ++o) {
        float a = c4[o];
        for (int k = 0; k < 20; ++k) a += z3[k] * A4[k * 5 + o];
        z4[o] = fmaxf(a, 0.f);
    }
    float a = c5[0];
    for (int k = 0; k < 5; ++k) a += z4[k] * A5[k];
    out[g] = fmaxf(a, 0.f);
}

extern "C" void kernel_launch(void* const* d_in, const int* in_sizes, int n_in,
                              void* d_out, int out_size, void* d_ws, size_t ws_size,
                              hipStream_t stream) {
    const float* x     = (const float*)d_in[0];
    const int*   edge  = (const int*)d_in[1];
    const int*   batch = (const int*)d_in[2];
    const float* u     = (const float*)d_in[3];
    const float* W1 = (const float*)d_in[4];  const float* b1 = (const float*)d_in[5];
    const float* W2 = (const float*)d_in[6];  const float* b2 = (const float*)d_in[7];
    const float* W3 = (const float*)d_in[8];  const float* b3 = (const float*)d_in[9];
    const float* A1 = (const float*)d_in[10]; const float* c1 = (const float*)d_in[11];
    const float* A2 = (const float*)d_in[12]; const float* c2 = (const float*)d_in[13];
    const float* A3 = (const float*)d_in[14]; const float* c3 = (const float*)d_in[15];
    const float* A4 = (const float*)d_in[16]; const float* c4 = (const float*)d_in[17];
    const float* A5 = (const float*)d_in[18]; const float* c5 = (const float*)d_in[19];

    const int N = in_sizes[2];          // 100000
    const int E = in_sizes[1] / 2;      // 3200000
    const int G = in_sizes[3] / 4;      // 256
    const int* src = edge;
    const int* dst = edge + E;

    // ---- workspace layout ----
    char* ws = (char*)d_ws;
    size_t off = 0;
    auto alloc = [&](size_t bytes) -> void* {
        void* p = ws + off;
        off = (off + bytes + 255) & ~(size_t)255;
        return p;
    };
    int*   counts    = (int*)alloc((size_t)N * 4);
    int*   rowstart  = (int*)alloc((size_t)N * 4);
    int*   cursor    = (int*)alloc((size_t)N * 4);
    int*   col       = (int*)alloc((size_t)E * 4);
    float* dnorm     = (float*)alloc((size_t)E * 4);
    float* dinv      = (float*)alloc((size_t)N * 4);
    float* hw        = (float*)alloc((size_t)N * H * 4);
    float* h         = (float*)alloc((size_t)N * H * 4);
    float* pool      = (float*)alloc((size_t)G * H * 4);
    float* cnt       = (float*)alloc((size_t)G * 4);
    int*   blockSums = (int*)alloc(512 * 4);

    const int nbN   = (N + 255) / 256;   // 391
    const int nbE   = (E + 255) / 256;   // 12500
    const int nbAgg = (N + 3) / 4;       // 25000 (4 waves/block, wave per node)

    // ---- zero state that is accumulated into ----
    zero_i32<<<nbN, 256, 0, stream>>>(counts, N);
    zero_f32<<<(G * H + G + 255) / 256, 256, 0, stream>>>(pool, G * H + G); // pool + cnt (contiguous)

    // ---- degree + dinv ----
    deg_count<<<nbE, 256, 0, stream>>>(dst, E, counts);
    pool_count<<<nbN, 256, 0, stream>>>(batch, cnt, N);
    compute_dinv<<<nbN, 256, 0, stream>>>(counts, dinv, N);

    // ---- CSR build (dst-indexed) ----
    scan_phase1<<<nbN, 256, 0, stream>>>(counts, rowstart, blockSums, N);
    scan_phase2<<<1, 512, 0, stream>>>(blockSums, nbN);
    scan_phase3<<<nbN, 256, 0, stream>>>(rowstart, cursor, blockSums, N);
    scatter_edges<<<nbE, 256, 0, stream>>>(src, dst, E, cursor, col);
    // cursor now holds row-end offsets
    build_dnorm<<<nbE, 256, 0, stream>>>(col, dinv, dnorm, E);

    // ---- conv1 ----
    lin_in<<<(N + 3) / 4, 256, 0, stream>>>(x, W1, hw, N);
    aggregate<false><<<nbAgg, 256, 0, stream>>>(hw, dinv, rowstart, cursor, col, dnorm, b1,
                                                h, batch, pool, N);
    // ---- conv2 ----
    lin_h<<<(N + 15) / 16, 256, 0, stream>>>(h, W2, hw, N);
    aggregate<false><<<nbAgg, 256, 0, stream>>>(hw, dinv, rowstart, cursor, col, dnorm, b2,
                                                h, batch, pool, N);
    // ---- conv3 (fused pooling accumulate) ----
    lin_h<<<(N + 15) / 16, 256, 0, stream>>>(h, W3, hw, N);
    aggregate<true><<<nbAgg, 256, 0, stream>>>(hw, dinv, rowstart, cursor, col, dnorm, b3,
                                               h, batch, pool, N);

    // ---- final MLP over 256 graphs ----
    mlp<<<1, 256, 0, stream>>>(pool, cnt, u, A1, c1, A2, c2, A3, c3, A4, c4, A5, c5,
                               (float*)d_out, G);
}

// Round 3
// 1051.661 us; speedup vs baseline: 1.5953x; 1.1356x over previous
//
#include <hip/hip_runtime.h>

#define H 64
#define BNODE_SHIFT 7           // 128 nodes per bucket
#define BNODES 128

// ---------------- zero-fill ----------------
__global__ void zero_i32(int* p, int n) {
    int i = blockIdx.x * blockDim.x + threadIdx.x;
    if (i < n) p[i] = 0;
}
__global__ void zero_f32(float* p, int n) {
    int i = blockIdx.x * blockDim.x + threadIdx.x;
    if (i < n) p[i] = 0.f;
}

// ---------------- bucket histogram (782 buckets, LDS-local then merge) ----------------
__global__ void bucket_hist(const int* __restrict__ dst, int E,
                            int* __restrict__ bcounts, int nbuck) {
    __shared__ int hist[800];
    for (int i = threadIdx.x; i < nbuck; i += blockDim.x) hist[i] = 0;
    __syncthreads();
    for (int e = blockIdx.x * blockDim.x + threadIdx.x; e < E; e += gridDim.x * blockDim.x)
        atomicAdd(&hist[dst[e] >> BNODE_SHIFT], 1);
    __syncthreads();
    for (int i = threadIdx.x; i < nbuck; i += blockDim.x) {
        int v = hist[i];
        if (v) atomicAdd(&bcounts[i], v);
    }
}

// ---------------- bucket offsets scan (1 block) ----------------
__global__ void bucket_scan(const int* __restrict__ bcounts, int* __restrict__ boff,
                            int* __restrict__ bcur, int* __restrict__ rowstart,
                            int nbuck, int E, int N) {
    __shared__ int t[1024];
    int tid = threadIdx.x;
    int v = (tid < nbuck) ? bcounts[tid] : 0;
    t[tid] = v;
    __syncthreads();
    for (int off = 1; off < 1024; off <<= 1) {
        int x = (tid >= off) ? t[tid - off] : 0;
        __syncthreads();
        t[tid] += x;
        __syncthreads();
    }
    if (tid < nbuck) {
        int o = t[tid] - v;       // exclusive
        boff[tid] = o;
        bcur[tid * 16] = o;       // 64B-padded cursor
    }
    if (tid == 0) { boff[nbuck] = E; rowstart[N] = E; }
}

// ---------------- phase A: scatter edges into bucket regions ----------------
__global__ void bucket_scatter(const int* __restrict__ src, const int* __restrict__ dst, int E,
                               int* __restrict__ bcur, int2* __restrict__ pairs) {
    int base = blockIdx.x * (blockDim.x * 4) + threadIdx.x;
    int d[4], s[4], p[4];
#pragma unroll
    for (int k = 0; k < 4; ++k) {
        int e = base + k * 256;
        d[k] = (e < E) ? dst[e] : -1;
        s[k] = (e < E) ? src[e] : 0;
    }
#pragma unroll
    for (int k = 0; k < 4; ++k)
        if (d[k] >= 0) p[k] = atomicAdd(&bcur[(d[k] >> BNODE_SHIFT) * 16], 1);
#pragma unroll
    for (int k = 0; k < 4; ++k)
        if (d[k] >= 0) pairs[p[k]] = make_int2(s[k], d[k]);
}

// ---------------- phase B: exact CSR within each bucket (LDS atomics) ----------------
__global__ void bucket_build(const int2* __restrict__ pairs, const int* __restrict__ boff,
                             int* __restrict__ col, int* __restrict__ rowstart,
                             float* __restrict__ dinv, int N) {
    __shared__ int hist[BNODES];
    __shared__ int cur[BNODES];
    int b = blockIdx.x;
    int lo = boff[b], hi = boff[b + 1];
    int node0 = b << BNODE_SHIFT;
    int tid = threadIdx.x;
    if (tid < BNODES) hist[tid] = 0;
    __syncthreads();
    for (int e = lo + tid; e < hi; e += 256)
        atomicAdd(&hist[pairs[e].y - node0], 1);
    __syncthreads();
    // exclusive scan over 128 counts (Hillis-Steele in 'cur')
    int v = (tid < BNODES) ? hist[tid] : 0;
    if (tid < BNODES) cur[tid] = v;
    __syncthreads();
    for (int off = 1; off < BNODES; off <<= 1) {
        int x = (tid >= off && tid < BNODES) ? cur[tid - off] : 0;
        __syncthreads();
        if (tid < BNODES) cur[tid] += x;
        __syncthreads();
    }
    if (tid < BNODES) {
        int ex = cur[tid] - v;    // exclusive
        int node = node0 + tid;
        if (node < N) {
            rowstart[node] = lo + ex;
            dinv[node] = rsqrtf((float)(v + 1));   // +1 self-loop
        }
        cur[tid] = ex;            // local cursor
    }
    __syncthreads();
    for (int e = lo + tid; e < hi; e += 256) {
        int2 pr = pairs[e];
        int p = atomicAdd(&cur[pr.y - node0], 1);
        col[lo + p] = pr.x;
    }
}

// ---------------- per-edge source norm (built once, reused by 3 convs) ----------------
__global__ void build_dnorm(const int* __restrict__ col, const float* __restrict__ dinv,
                            float* __restrict__ dnorm, int E) {
    int p = blockIdx.x * blockDim.x + threadIdx.x;
    if (p < E) dnorm[p] = dinv[col[p]];
}

// ---------------- pool counts ----------------
__global__ void pool_count(const int* __restrict__ batch, float* __restrict__ cnt, int N) {
    int i = blockIdx.x * blockDim.x + threadIdx.x;
    if (i < N) atomicAdd(&cnt[batch[i]], 1.f);
}

// ---------------- linear: N x 9 @ 9 x 64 ----------------
__global__ void lin_in(const float* __restrict__ x, const float* __restrict__ W,
                       float* __restrict__ out, int N) {
    __shared__ float Ws[9 * H];
    __shared__ float xs[4 * 9];
    int tid = threadIdx.x;
    for (int idx = tid; idx < 9 * H; idx += 256) Ws[idx] = W[idx];
    int node0 = blockIdx.x * 4;
    for (int idx = tid; idx < 4 * 9; idx += 256) {
        int nl = idx / 9, k = idx % 9;
        int n = node0 + nl;
        xs[idx] = (n < N) ? x[n * 9 + k] : 0.f;
    }
    __syncthreads();
    int nl = tid >> 6, f = tid & 63;
    int n = node0 + nl;
    float acc = 0.f;
#pragma unroll
    for (int k = 0; k < 9; ++k) acc += xs[nl * 9 + k] * Ws[k * H + f];
    if (n < N) out[n * H + f] = acc;
}

// ---------------- linear: N x 64 @ 64 x 64 (16 nodes/block) ----------------
__global__ void lin_h(const float* __restrict__ h, const float* __restrict__ W,
                      float* __restrict__ out, int N) {
    __shared__ float Ws[H * H];     // 16 KB
    __shared__ float hs[16 * H];    // 4 KB
    int tid = threadIdx.x;
    int node0 = blockIdx.x * 16;
    for (int idx = tid; idx < H * H; idx += 256) Ws[idx] = W[idx];
    for (int idx = tid; idx < 16 * H; idx += 256) {
        int n = node0 + (idx >> 6);
        hs[idx] = (n < N) ? h[n * H + (idx & 63)] : 0.f;
    }
    __syncthreads();
    int nlb = tid >> 6, f = tid & 63;
    float a0 = 0.f, a1 = 0.f, a2 = 0.f, a3 = 0.f;
#pragma unroll 8
    for (int k = 0; k < H; ++k) {
        float w = Ws[k * H + f];
        a0 += hs[(nlb) * H + k] * w;
        a1 += hs[(nlb + 4) * H + k] * w;
        a2 += hs[(nlb + 8) * H + k] * w;
        a3 += hs[(nlb + 12) * H + k] * w;
    }
    int n;
    n = node0 + nlb;      if (n < N) out[n * H + f] = a0;
    n = node0 + nlb + 4;  if (n < N) out[n * H + f] = a1;
    n = node0 + nlb + 8;  if (n < N) out[n * H + f] = a2;
    n = node0 + nlb + 12; if (n < N) out[n * H + f] = a3;
}

// ---------------- aggregate: one wave per node, lane = feature ----------------
template <bool POOL>
__global__ void aggregate(const float* __restrict__ hw, const float* __restrict__ dinv,
                          const int* __restrict__ rowstart, const int* __restrict__ rowend,
                          const int* __restrict__ col, const float* __restrict__ dnorm,
                          const float* __restrict__ bias,
                          float* __restrict__ out, const int* __restrict__ batch,
                          float* __restrict__ pool, int N) {
    int gtid = blockIdx.x * blockDim.x + threadIdx.x;
    int i = gtid >> 6;       // node = wave
    int f = threadIdx.x & 63;
    if (i >= N) return;
    float di = dinv[i];
    float acc = di * hw[(size_t)i * H + f];  // self-loop term (x di again at the end)
    int s = rowstart[i], e = rowend[i];
    for (int base = s; base < e; base += 64) {
        int cnt = e - base;
        if (cnt > 64) cnt = 64;
        int   idx = 0;
        float dn  = 0.f;
        if (f < cnt) {
            idx = col[base + f];     // coalesced 64-wide index load
            dn  = dnorm[base + f];   // coalesced 64-wide norm load
        }
        int j = 0;
        for (; j + 4 <= cnt; j += 4) {
            int s0 = __shfl(idx, j);     int s1 = __shfl(idx, j + 1);
            int s2 = __shfl(idx, j + 2); int s3 = __shfl(idx, j + 3);
            float d0 = __shfl(dn, j);     float d1 = __shfl(dn, j + 1);
            float d2 = __shfl(dn, j + 2); float d3 = __shfl(dn, j + 3);
            float v0 = hw[(size_t)s0 * H + f];
            float v1 = hw[(size_t)s1 * H + f];
            float v2 = hw[(size_t)s2 * H + f];
            float v3 = hw[(size_t)s3 * H + f];
            acc = fmaf(d0, v0, acc);
            acc = fmaf(d1, v1, acc);
            acc = fmaf(d2, v2, acc);
            acc = fmaf(d3, v3, acc);
        }
        for (; j < cnt; ++j) {
            int   s0 = __shfl(idx, j);
            float d0 = __shfl(dn, j);
            acc = fmaf(d0, hw[(size_t)s0 * H + f], acc);
        }
    }
    float val = fmaxf(bias[f] + di * acc, 0.f);
    if (POOL) {
        atomicAdd(&pool[batch[i] * H + f], val);
    } else {
        out[(size_t)i * H + f] = val;
    }
}

// ---------------- final MLP: one thread per graph ----------------
__global__ void mlp(const float* __restrict__ pool, const float* __restrict__ cnt,
                    const float* __restrict__ u,
                    const float* __restrict__ A1, const float* __restrict__ c1,
                    const float* __restrict__ A2, const float* __restrict__ c2,
                    const float* __restrict__ A3, const float* __restrict__ c3,
                    const float* __restrict__ A4, const float* __restrict__ c4,
                    const float* __restrict__ A5, const float* __restrict__ c5,
                    float* __restrict__ out, int G) {
    int g = blockIdx.x * blockDim.x + threadIdx.x;
    if (g >= G) return;
    float z[68];
    float inv = 1.f / fmaxf(cnt[g], 1.f);
#pragma unroll
    for (int k = 0; k < H; ++k) z[k] = pool[g * H + k] * inv;
#pragma unroll
    for (int k = 0; k < 4; ++k) z[H + k] = u[g * 4 + k];

    float z1[50];
    for (int o = 0; o < 50; ++o) {
        float a = c1[o];
        for (int k = 0; k < 68; ++k) a += z[k] * A1[k * 50 + o];
        z1[o] = fmaxf(a, 0.f);
    }
    float z2[30];
    for (int o = 0; o < 30; ++o) {
        float a = c2[o];
        for (int k = 0; k < 50; ++k) a += z1[k] * A2[k * 30 + o];
        z2[o] = fmaxf(a, 0.f);
    }
    float z3[20];
    for (int o = 0; o < 20; ++o) {
        float a = c3[o];
        for (int k = 0; k < 30; ++k) a += z2[k] * A3[k * 20 + o];
        z3[o] = fmaxf(a, 0.f);
    }
    float z4[5];
    for (int o = 0; o < 5; ++o) {
        float a = c4[o];
        for (int k = 0; k < 20; ++k) a += z3[k] * A4[k * 5 + o];
        z4[o] = fmaxf(a, 0.f);
    }
    float a = c5[0];
    for (int k = 0; k < 5; ++k) a += z4[k] * A5[k];
    out[g] = fmaxf(a, 0.f);
}

extern "C" void kernel_launch(void* const* d_in, const int* in_sizes, int n_in,
                              void* d_out, int out_size, void* d_ws, size_t ws_size,
                              hipStream_t stream) {
    const float* x     = (const float*)d_in[0];
    const int*   edge  = (const int*)d_in[1];
    const int*   batch = (const int*)d_in[2];
    const float* u     = (const float*)d_in[3];
    const float* W1 = (const float*)d_in[4];  const float* b1 = (const float*)d_in[5];
    const float* W2 = (const float*)d_in[6];  const float* b2 = (const float*)d_in[7];
    const float* W3 = (const float*)d_in[8];  const float* b3 = (const float*)d_in[9];
    const float* A1 = (const float*)d_in[10]; const float* c1 = (const float*)d_in[11];
    const float* A2 = (const float*)d_in[12]; const float* c2 = (const float*)d_in[13];
    const float* A3 = (const float*)d_in[14]; const float* c3 = (const float*)d_in[15];
    const float* A4 = (const float*)d_in[16]; const float* c4 = (const float*)d_in[17];
    const float* A5 = (const float*)d_in[18]; const float* c5 = (const float*)d_in[19];

    const int N = in_sizes[2];          // 100000
    const int E = in_sizes[1] / 2;      // 3200000
    const int G = in_sizes[3] / 4;      // 256
    const int* src = edge;
    const int* dst = edge + E;
    const int nbuck = (N + BNODES - 1) >> BNODE_SHIFT;   // 782

    // ---- workspace layout (pairs region aliased with hw: pairs dead before lin_in) ----
    char* ws = (char*)d_ws;
    size_t off = 0;
    auto alloc = [&](size_t bytes) -> void* {
        void* p = ws + off;
        off = (off + bytes + 255) & ~(size_t)255;
        return p;
    };
    float* hw        = (float*)alloc((size_t)N * H * 4);   // also 'pairs' (E*8 = 25.6MB <= N*H*4)
    float* h         = (float*)alloc((size_t)N * H * 4);
    int*   col       = (int*)alloc((size_t)E * 4);
    float* dnorm     = (float*)alloc((size_t)E * 4);
    int*   rowstart  = (int*)alloc((size_t)(N + 1) * 4);
    float* dinv      = (float*)alloc((size_t)N * 4);
    int*   bcounts   = (int*)alloc((size_t)nbuck * 4);
    int*   boff      = (int*)alloc((size_t)(nbuck + 1) * 4);
    int*   bcur      = (int*)alloc((size_t)nbuck * 64);    // 64B-padded cursors
    float* pool      = (float*)alloc((size_t)G * H * 4);
    float* cnt       = (float*)alloc((size_t)G * 4);
    int2*  pairs     = (int2*)hw;

    const int nbN   = (N + 255) / 256;
    const int nbE   = (E + 255) / 256;
    const int nbAgg = (N + 3) / 4;       // 4 waves/block, wave per node

    // ---- zero accumulated state ----
    zero_i32<<<(nbuck + 255) / 256, 256, 0, stream>>>(bcounts, nbuck);
    zero_f32<<<(G * H + G + 255) / 256, 256, 0, stream>>>(pool, G * H + G); // pool + cnt contiguous

    // ---- CSR build via bucket sort ----
    bucket_hist<<<256, 256, 0, stream>>>(dst, E, bcounts, nbuck);
    bucket_scan<<<1, 1024, 0, stream>>>(bcounts, boff, bcur, rowstart, nbuck, E, N);
    bucket_scatter<<<(E + 1023) / 1024, 256, 0, stream>>>(src, dst, E, bcur, pairs);
    bucket_build<<<nbuck, 256, 0, stream>>>(pairs, boff, col, rowstart, dinv, N);
    build_dnorm<<<nbE, 256, 0, stream>>>(col, dinv, dnorm, E);
    pool_count<<<nbN, 256, 0, stream>>>(batch, cnt, N);

    // ---- conv1 ----
    lin_in<<<(N + 3) / 4, 256, 0, stream>>>(x, W1, hw, N);
    aggregate<false><<<nbAgg, 256, 0, stream>>>(hw, dinv, rowstart, rowstart + 1, col, dnorm, b1,
                                                h, batch, pool, N);
    // ---- conv2 ----
    lin_h<<<(N + 15) / 16, 256, 0, stream>>>(h, W2, hw, N);
    aggregate<false><<<nbAgg, 256, 0, stream>>>(hw, dinv, rowstart, rowstart + 1, col, dnorm, b2,
                                                h, batch, pool, N);
    // ---- conv3 (fused pooling accumulate) ----
    lin_h<<<(N + 15) / 16, 256, 0, stream>>>(h, W3, hw, N);
    aggregate<true><<<nbAgg, 256, 0, stream>>>(hw, dinv, rowstart, rowstart + 1, col, dnorm, b3,
                                               h, batch, pool, N);

    // ---- final MLP over 256 graphs ----
    mlp<<<1, 256, 0, stream>>>(pool, cnt, u, A1, c1, A2, c2, A3, c3, A4, c4, A5, c5,
                               (float*)d_out, G);
}

// Round 4
// 700.709 us; speedup vs baseline: 2.3944x; 1.5009x over previous
//
#include <hip/hip_runtime.h>

#define H 64
#define BNODE_SHIFT 7           // 128 nodes per bucket
#define BNODES 128

// ---------------- zero-fill ----------------
__global__ void zero_i32(int* p, int n) {
    int i = blockIdx.x * blockDim.x + threadIdx.x;
    if (i < n) p[i] = 0;
}

// ---------------- bucket histogram (782 buckets, LDS-local then merge) ----------------
__global__ void bucket_hist(const int* __restrict__ dst, int E,
                            int* __restrict__ bcounts, int nbuck) {
    __shared__ int hist[800];
    for (int i = threadIdx.x; i < nbuck; i += blockDim.x) hist[i] = 0;
    __syncthreads();
    for (int e = blockIdx.x * blockDim.x + threadIdx.x; e < E; e += gridDim.x * blockDim.x)
        atomicAdd(&hist[dst[e] >> BNODE_SHIFT], 1);
    __syncthreads();
    for (int i = threadIdx.x; i < nbuck; i += blockDim.x) {
        int v = hist[i];
        if (v) atomicAdd(&bcounts[i], v);
    }
}

// ---------------- bucket offsets scan (1 block) ----------------
__global__ void bucket_scan(const int* __restrict__ bcounts, int* __restrict__ boff,
                            int* __restrict__ bcur, int* __restrict__ rowstart,
                            int nbuck, int E, int N) {
    __shared__ int t[1024];
    int tid = threadIdx.x;
    int v = (tid < nbuck) ? bcounts[tid] : 0;
    t[tid] = v;
    __syncthreads();
    for (int off = 1; off < 1024; off <<= 1) {
        int x = (tid >= off) ? t[tid - off] : 0;
        __syncthreads();
        t[tid] += x;
        __syncthreads();
    }
    if (tid < nbuck) {
        int o = t[tid] - v;       // exclusive
        boff[tid] = o;
        bcur[tid * 16] = o;       // 64B-padded cursor
    }
    if (tid == 0) { boff[nbuck] = E; rowstart[N] = E; }
}

// ---------------- phase A: scatter edges into bucket regions ----------------
__global__ void bucket_scatter(const int* __restrict__ src, const int* __restrict__ dst, int E,
                               int* __restrict__ bcur, int2* __restrict__ pairs) {
    int base = blockIdx.x * (blockDim.x * 4) + threadIdx.x;
    int d[4], s[4], p[4];
#pragma unroll
    for (int k = 0; k < 4; ++k) {
        int e = base + k * 256;
        d[k] = (e < E) ? dst[e] : -1;
        s[k] = (e < E) ? src[e] : 0;
    }
#pragma unroll
    for (int k = 0; k < 4; ++k)
        if (d[k] >= 0) p[k] = atomicAdd(&bcur[(d[k] >> BNODE_SHIFT) * 16], 1);
#pragma unroll
    for (int k = 0; k < 4; ++k)
        if (d[k] >= 0) pairs[p[k]] = make_int2(s[k], d[k]);
}

// ---------------- phase B: exact CSR within each bucket (LDS atomics) ----------------
__global__ void bucket_build(const int2* __restrict__ pairs, const int* __restrict__ boff,
                             int* __restrict__ col, int* __restrict__ rowstart,
                             float* __restrict__ dinv, int N) {
    __shared__ int hist[BNODES];
    __shared__ int cur[BNODES];
    int b = blockIdx.x;
    int lo = boff[b], hi = boff[b + 1];
    int node0 = b << BNODE_SHIFT;
    int tid = threadIdx.x;
    if (tid < BNODES) hist[tid] = 0;
    __syncthreads();
    for (int e = lo + tid; e < hi; e += 256)
        atomicAdd(&hist[pairs[e].y - node0], 1);
    __syncthreads();
    int v = (tid < BNODES) ? hist[tid] : 0;
    if (tid < BNODES) cur[tid] = v;
    __syncthreads();
    for (int off = 1; off < BNODES; off <<= 1) {
        int x = (tid >= off && tid < BNODES) ? cur[tid - off] : 0;
        __syncthreads();
        if (tid < BNODES) cur[tid] += x;
        __syncthreads();
    }
    if (tid < BNODES) {
        int ex = cur[tid] - v;    // exclusive
        int node = node0 + tid;
        if (node < N) {
            rowstart[node] = lo + ex;
            dinv[node] = rsqrtf((float)(v + 1));   // +1 self-loop
        }
        cur[tid] = ex;            // local cursor
    }
    __syncthreads();
    for (int e = lo + tid; e < hi; e += 256) {
        int2 pr = pairs[e];
        int p = atomicAdd(&cur[pr.y - node0], 1);
        col[lo + p] = pr.x;
    }
}

// ---------------- per-edge source norm (built once, reused by 3 convs) ----------------
__global__ void build_dnorm(const int* __restrict__ col, const float* __restrict__ dinv,
                            float* __restrict__ dnorm, int E) {
    int p = blockIdx.x * blockDim.x + threadIdx.x;
    if (p < E) dnorm[p] = dinv[col[p]];
}

// ---------------- graph boundaries from sorted batch (no atomics) ----------------
__global__ void graph_bounds(const int* __restrict__ batch, int* __restrict__ nodestart,
                             int N, int G) {
    int i = blockIdx.x * blockDim.x + threadIdx.x;
    if (i >= N) return;
    int b = batch[i];
    int bp = (i == 0) ? -1 : batch[i - 1];
    for (int g = bp + 1; g <= b; ++g) nodestart[g] = i;
    if (i == N - 1) nodestart[G] = N;
}

// ---------------- segmented mean pool: one block per graph ----------------
__global__ void pool_mean(const float* __restrict__ h, const int* __restrict__ nodestart,
                          float* __restrict__ pooled, int G) {
    int g = blockIdx.x;
    int lo = nodestart[g], hi = nodestart[g + 1];
    int f = threadIdx.x & 63, w = threadIdx.x >> 6;
    float acc = 0.f;
    for (int n = lo + w; n < hi; n += 4) acc += h[(size_t)n * H + f];
    __shared__ float red[4][64];
    red[w][f] = acc;
    __syncthreads();
    if (w == 0) {
        float s = red[0][f] + red[1][f] + red[2][f] + red[3][f];
        float c = (float)(hi - lo);
        pooled[g * H + f] = s / fmaxf(c, 1.f);
    }
}

// ---------------- linear: N x 9 @ 9 x 64 ----------------
__global__ void lin_in(const float* __restrict__ x, const float* __restrict__ W,
                       float* __restrict__ out, int N) {
    __shared__ float Ws[9 * H];
    __shared__ float xs[4 * 9];
    int tid = threadIdx.x;
    for (int idx = tid; idx < 9 * H; idx += 256) Ws[idx] = W[idx];
    int node0 = blockIdx.x * 4;
    for (int idx = tid; idx < 4 * 9; idx += 256) {
        int nl = idx / 9, k = idx % 9;
        int n = node0 + nl;
        xs[idx] = (n < N) ? x[n * 9 + k] : 0.f;
    }
    __syncthreads();
    int nl = tid >> 6, f = tid & 63;
    int n = node0 + nl;
    float acc = 0.f;
#pragma unroll
    for (int k = 0; k < 9; ++k) acc += xs[nl * 9 + k] * Ws[k * H + f];
    if (n < N) out[n * H + f] = acc;
}

// ---------------- linear: N x 64 @ 64 x 64 (16 nodes/block) ----------------
__global__ void lin_h(const float* __restrict__ h, const float* __restrict__ W,
                      float* __restrict__ out, int N) {
    __shared__ float Ws[H * H];     // 16 KB
    __shared__ float hs[16 * H];    // 4 KB
    int tid = threadIdx.x;
    int node0 = blockIdx.x * 16;
    for (int idx = tid; idx < H * H; idx += 256) Ws[idx] = W[idx];
    for (int idx = tid; idx < 16 * H; idx += 256) {
        int n = node0 + (idx >> 6);
        hs[idx] = (n < N) ? h[n * H + (idx & 63)] : 0.f;
    }
    __syncthreads();
    int nlb = tid >> 6, f = tid & 63;
    float a0 = 0.f, a1 = 0.f, a2 = 0.f, a3 = 0.f;
#pragma unroll 8
    for (int k = 0; k < H; ++k) {
        float w = Ws[k * H + f];
        a0 += hs[(nlb) * H + k] * w;
        a1 += hs[(nlb + 4) * H + k] * w;
        a2 += hs[(nlb + 8) * H + k] * w;
        a3 += hs[(nlb + 12) * H + k] * w;
    }
    int n;
    n = node0 + nlb;      if (n < N) out[n * H + f] = a0;
    n = node0 + nlb + 4;  if (n < N) out[n * H + f] = a1;
    n = node0 + nlb + 8;  if (n < N) out[n * H + f] = a2;
    n = node0 + nlb + 12; if (n < N) out[n * H + f] = a3;
}

// ---------------- aggregate: one wave per node, lane = feature ----------------
__global__ void aggregate(const float* __restrict__ hw, const float* __restrict__ dinv,
                          const int* __restrict__ rowstart, const int* __restrict__ rowend,
                          const int* __restrict__ col, const float* __restrict__ dnorm,
                          const float* __restrict__ bias,
                          float* __restrict__ out, int N) {
    int gtid = blockIdx.x * blockDim.x + threadIdx.x;
    int i = gtid >> 6;       // node = wave
    int f = threadIdx.x & 63;
    if (i >= N) return;
    float di = dinv[i];
    float acc = di * hw[(size_t)i * H + f];  // self-loop term (x di again at the end)
    int s = rowstart[i], e = rowend[i];
    for (int base = s; base < e; base += 64) {
        int cnt = e - base;
        if (cnt > 64) cnt = 64;
        int   idx = 0;
        float dn  = 0.f;
        if (f < cnt) {
            idx = col[base + f];     // coalesced 64-wide index load
            dn  = dnorm[base + f];   // coalesced 64-wide norm load
        }
        int j = 0;
        for (; j + 4 <= cnt; j += 4) {
            int s0 = __shfl(idx, j);     int s1 = __shfl(idx, j + 1);
            int s2 = __shfl(idx, j + 2); int s3 = __shfl(idx, j + 3);
            float d0 = __shfl(dn, j);     float d1 = __shfl(dn, j + 1);
            float d2 = __shfl(dn, j + 2); float d3 = __shfl(dn, j + 3);
            float v0 = hw[(size_t)s0 * H + f];
            float v1 = hw[(size_t)s1 * H + f];
            float v2 = hw[(size_t)s2 * H + f];
            float v3 = hw[(size_t)s3 * H + f];
            acc = fmaf(d0, v0, acc);
            acc = fmaf(d1, v1, acc);
            acc = fmaf(d2, v2, acc);
            acc = fmaf(d3, v3, acc);
        }
        for (; j < cnt; ++j) {
            int   s0 = __shfl(idx, j);
            float d0 = __shfl(dn, j);
            acc = fmaf(d0, hw[(size_t)s0 * H + f], acc);
        }
    }
    out[(size_t)i * H + f] = fmaxf(bias[f] + di * acc, 0.f);
}

// ---------------- final MLP: one wave per graph, shfl-based ----------------
__global__ void mlp(const float* __restrict__ pooled, const float* __restrict__ u,
                    const float* __restrict__ A1, const float* __restrict__ c1,
                    const float* __restrict__ A2, const float* __restrict__ c2,
                    const float* __restrict__ A3, const float* __restrict__ c3,
                    const float* __restrict__ A4, const float* __restrict__ c4,
                    const float* __restrict__ A5, const float* __restrict__ c5,
                    float* __restrict__ out, int G) {
    int wid = (blockIdx.x * blockDim.x + threadIdx.x) >> 6;  // wave = graph
    int lane = threadIdx.x & 63;
    if (wid >= G) return;
    int g = wid;

    float zreg = pooled[g * H + lane];          // lane k holds z[k], k<64
    float u0 = u[g * 4 + 0], u1 = u[g * 4 + 1], u2 = u[g * 4 + 2], u3 = u[g * 4 + 3];

    // layer 1: 68 -> 50
    float acc = (lane < 50) ? c1[lane] : 0.f;
#pragma unroll
    for (int k = 0; k < 64; ++k) {
        float zk = __shfl(zreg, k);
        float w = (lane < 50) ? A1[k * 50 + lane] : 0.f;
        acc = fmaf(zk, w, acc);
    }
    {
        float w;
        w = (lane < 50) ? A1[64 * 50 + lane] : 0.f; acc = fmaf(u0, w, acc);
        w = (lane < 50) ? A1[65 * 50 + lane] : 0.f; acc = fmaf(u1, w, acc);
        w = (lane < 50) ? A1[66 * 50 + lane] : 0.f; acc = fmaf(u2, w, acc);
        w = (lane < 50) ? A1[67 * 50 + lane] : 0.f; acc = fmaf(u3, w, acc);
    }
    float z1v = fmaxf(acc, 0.f);

    // layer 2: 50 -> 30
    acc = (lane < 30) ? c2[lane] : 0.f;
#pragma unroll
    for (int k = 0; k < 50; ++k) {
        float zk = __shfl(z1v, k);
        float w = (lane < 30) ? A2[k * 30 + lane] : 0.f;
        acc = fmaf(zk, w, acc);
    }
    float z2v = fmaxf(acc, 0.f);

    // layer 3: 30 -> 20
    acc = (lane < 20) ? c3[lane] : 0.f;
#pragma unroll
    for (int k = 0; k < 30; ++k) {
        float zk = __shfl(z2v, k);
        float w = (lane < 20) ? A3[k * 20 + lane] : 0.f;
        acc = fmaf(zk, w, acc);
    }
    float z3v = fmaxf(acc, 0.f);

    // layer 4: 20 -> 5
    acc = (lane < 5) ? c4[lane] : 0.f;
#pragma unroll
    for (int k = 0; k < 20; ++k) {
        float zk = __shfl(z3v, k);
        float w = (lane < 5) ? A4[k * 5 + lane] : 0.f;
        acc = fmaf(zk, w, acc);
    }
    float z4v = fmaxf(acc, 0.f);

    // layer 5: 5 -> 1
    acc = c5[0];
#pragma unroll
    for (int k = 0; k < 5; ++k) {
        float zk = __shfl(z4v, k);
        acc = fmaf(zk, A5[k], acc);
    }
    if (lane == 0) out[g] = fmaxf(acc, 0.f);
}

extern "C" void kernel_launch(void* const* d_in, const int* in_sizes, int n_in,
                              void* d_out, int out_size, void* d_ws, size_t ws_size,
                              hipStream_t stream) {
    const float* x     = (const float*)d_in[0];
    const int*   edge  = (const int*)d_in[1];
    const int*   batch = (const int*)d_in[2];
    const float* u     = (const float*)d_in[3];
    const float* W1 = (const float*)d_in[4];  const float* b1 = (const float*)d_in[5];
    const float* W2 = (const float*)d_in[6];  const float* b2 = (const float*)d_in[7];
    const float* W3 = (const float*)d_in[8];  const float* b3 = (const float*)d_in[9];
    const float* A1 = (const float*)d_in[10]; const float* c1 = (const float*)d_in[11];
    const float* A2 = (const float*)d_in[12]; const float* c2 = (const float*)d_in[13];
    const float* A3 = (const float*)d_in[14]; const float* c3 = (const float*)d_in[15];
    const float* A4 = (const float*)d_in[16]; const float* c4 = (const float*)d_in[17];
    const float* A5 = (const float*)d_in[18]; const float* c5 = (const float*)d_in[19];

    const int N = in_sizes[2];          // 100000
    const int E = in_sizes[1] / 2;      // 3200000
    const int G = in_sizes[3] / 4;      // 256
    const int* src = edge;
    const int* dst = edge + E;
    const int nbuck = (N + BNODES - 1) >> BNODE_SHIFT;   // 782

    // ---- workspace layout (pairs region aliased with hw: pairs dead before lin_in) ----
    char* ws = (char*)d_ws;
    size_t off = 0;
    auto alloc = [&](size_t bytes) -> void* {
        void* p = ws + off;
        off = (off + bytes + 255) & ~(size_t)255;
        return p;
    };
    float* hw        = (float*)alloc((size_t)N * H * 4);   // also 'pairs' (E*8 = 25.6MB <= N*H*4)
    float* h         = (float*)alloc((size_t)N * H * 4);
    int*   col       = (int*)alloc((size_t)E * 4);
    float* dnorm     = (float*)alloc((size_t)E * 4);
    int*   rowstart  = (int*)alloc((size_t)(N + 1) * 4);
    float* dinv      = (float*)alloc((size_t)N * 4);
    int*   bcounts   = (int*)alloc((size_t)nbuck * 4);
    int*   boff      = (int*)alloc((size_t)(nbuck + 1) * 4);
    int*   bcur      = (int*)alloc((size_t)nbuck * 64);    // 64B-padded cursors
    int*   nodestart = (int*)alloc((size_t)(G + 1) * 4);
    float* pooled    = (float*)alloc((size_t)G * H * 4);
    int2*  pairs     = (int2*)hw;

    const int nbN   = (N + 255) / 256;
    const int nbE   = (E + 255) / 256;
    const int nbAgg = (N + 3) / 4;       // 4 waves/block, wave per node

    // ---- CSR build via bucket sort ----
    zero_i32<<<(nbuck + 255) / 256, 256, 0, stream>>>(bcounts, nbuck);
    bucket_hist<<<256, 256, 0, stream>>>(dst, E, bcounts, nbuck);
    bucket_scan<<<1, 1024, 0, stream>>>(bcounts, boff, bcur, rowstart, nbuck, E, N);
    bucket_scatter<<<(E + 1023) / 1024, 256, 0, stream>>>(src, dst, E, bcur, pairs);
    bucket_build<<<nbuck, 256, 0, stream>>>(pairs, boff, col, rowstart, dinv, N);
    build_dnorm<<<nbE, 256, 0, stream>>>(col, dinv, dnorm, E);
    graph_bounds<<<nbN, 256, 0, stream>>>(batch, nodestart, N, G);

    // ---- conv1 ----
    lin_in<<<(N + 3) / 4, 256, 0, stream>>>(x, W1, hw, N);
    aggregate<<<nbAgg, 256, 0, stream>>>(hw, dinv, rowstart, rowstart + 1, col, dnorm, b1, h, N);
    // ---- conv2 ----
    lin_h<<<(N + 15) / 16, 256, 0, stream>>>(h, W2, hw, N);
    aggregate<<<nbAgg, 256, 0, stream>>>(hw, dinv, rowstart, rowstart + 1, col, dnorm, b2, h, N);
    // ---- conv3 ----
    lin_h<<<(N + 15) / 16, 256, 0, stream>>>(h, W3, hw, N);
    aggregate<<<nbAgg, 256, 0, stream>>>(hw, dinv, rowstart, rowstart + 1, col, dnorm, b3, h, N);

    // ---- mean pool + final MLP ----
    pool_mean<<<G, 256, 0, stream>>>(h, nodestart, pooled, G);
    mlp<<<(G * 64 + 255) / 256, 256, 0, stream>>>(pooled, u, A1, c1, A2, c2, A3, c3,
                                                  A4, c4, A5, c5, (float*)d_out, G);
}

// Round 5
// 558.725 us; speedup vs baseline: 3.0028x; 1.2541x over previous
//
#include <hip/hip_runtime.h>

#define H 64
#define BNODE_SHIFT 8           // 256 nodes per bucket
#define BNODES 256
#define CHUNK 12288             // edges per sort block (48 per thread)
#define EPT 48

// ---------------- zero-fill ----------------
__global__ void zero_i32(int* p, int n) {
    int i = blockIdx.x * blockDim.x + threadIdx.x;
    if (i < n) p[i] = 0;
}

// ---------------- bucket histogram (LDS-local then merge) ----------------
__global__ void bucket_hist(const int* __restrict__ dst, int E,
                            int* __restrict__ bcounts, int nbuck) {
    __shared__ int hist[512];
    for (int i = threadIdx.x; i < nbuck; i += blockDim.x) hist[i] = 0;
    __syncthreads();
    for (int e = blockIdx.x * blockDim.x + threadIdx.x; e < E; e += gridDim.x * blockDim.x)
        atomicAdd(&hist[dst[e] >> BNODE_SHIFT], 1);
    __syncthreads();
    for (int i = threadIdx.x; i < nbuck; i += blockDim.x) {
        int v = hist[i];
        if (v) atomicAdd(&bcounts[i], v);
    }
}

// ---------------- bucket offsets scan (1 block) ----------------
__global__ void bucket_scan(const int* __restrict__ bcounts, int* __restrict__ boff,
                            int* __restrict__ bcur, int* __restrict__ rowstart,
                            int nbuck, int E, int N) {
    __shared__ int t[1024];
    int tid = threadIdx.x;
    int v = (tid < nbuck) ? bcounts[tid] : 0;
    t[tid] = v;
    __syncthreads();
    for (int off = 1; off < 1024; off <<= 1) {
        int x = (tid >= off) ? t[tid - off] : 0;
        __syncthreads();
        t[tid] += x;
        __syncthreads();
    }
    if (tid < nbuck) {
        int o = t[tid] - v;       // exclusive
        boff[tid] = o;
        bcur[tid * 16] = o;       // 64B-padded cursor
    }
    if (tid == 0) { boff[nbuck] = E; rowstart[N] = E; }
}

// ---------------- block-local LDS sort + coalesced flush ----------------
// pack: src (bits 0..19) | local_dst (bits 20..27)
__global__ void edge_sort_scatter(const int* __restrict__ src, const int* __restrict__ dst,
                                  int E, int nbuck,
                                  int* __restrict__ bcur, int* __restrict__ pairs4) {
    __shared__ int hist[392];
    __shared__ int bstart[393];
    __shared__ int cur[392];
    __shared__ int gbase[392];
    __shared__ int wsum[256];
    __shared__ int packed[CHUNK];   // 48 KB

    int t = threadIdx.x;
    int chunkBase = blockIdx.x * CHUNK;

    // phase 1: local histogram
    for (int i = t; i < nbuck; i += 256) hist[i] = 0;
    __syncthreads();
    for (int k = 0; k < EPT; ++k) {
        int e = chunkBase + t + k * 256;
        if (e < E) atomicAdd(&hist[dst[e] >> BNODE_SHIFT], 1);
    }
    __syncthreads();

    // phase 2: exclusive scan of hist (2 items/thread covers <=512 buckets)
    int a0 = (2 * t < nbuck) ? hist[2 * t] : 0;
    int a1 = (2 * t + 1 < nbuck) ? hist[2 * t + 1] : 0;
    int s2 = a0 + a1;
    wsum[t] = s2;
    __syncthreads();
    for (int off = 1; off < 256; off <<= 1) {
        int x = (t >= off) ? wsum[t - off] : 0;
        __syncthreads();
        wsum[t] += x;
        __syncthreads();
    }
    int base = wsum[t] - s2;        // exclusive
    if (2 * t < nbuck)     bstart[2 * t] = base;
    if (2 * t + 1 < nbuck) bstart[2 * t + 1] = base + a0;
    if (t == 255) bstart[nbuck] = wsum[255];   // chunk edge count
    __syncthreads();

    // phase 2b: reserve global spans; init local cursors
    for (int b = t; b < nbuck; b += 256) {
        int cnt = bstart[b + 1] - bstart[b];
        gbase[b] = cnt ? atomicAdd(&bcur[b * 16], cnt) : 0;
        cur[b] = bstart[b];
    }
    __syncthreads();

    // phase 3: place edges sorted into LDS (re-read edges; L2-hot)
    for (int k = 0; k < EPT; ++k) {
        int e = chunkBase + t + k * 256;
        if (e < E) {
            int d = dst[e];
            int b = d >> BNODE_SHIFT;
            int pos = atomicAdd(&cur[b], 1);
            packed[pos] = src[e] | ((d & (BNODES - 1)) << 20);
        }
    }
    __syncthreads();

    // phase 4: coalesced flush, one bucket run per wave
    int w = t >> 6, lane = t & 63;
    for (int b = w; b < nbuck; b += 4) {
        int lb = bstart[b], le = bstart[b + 1];
        int gb = gbase[b];
        for (int j = lb + lane; j < le; j += 64)
            pairs4[gb + (j - lb)] = packed[j];
    }
}

// ---------------- exact CSR within each bucket (LDS atomics) ----------------
__global__ void bucket_build(const int* __restrict__ pairs4, const int* __restrict__ boff,
                             int* __restrict__ col, int* __restrict__ rowstart,
                             float* __restrict__ dinv, int N) {
    __shared__ int hist[BNODES];
    __shared__ int cur[BNODES];
    int b = blockIdx.x;
    int lo = boff[b], hi = boff[b + 1];
    int node0 = b << BNODE_SHIFT;
    int tid = threadIdx.x;
    hist[tid] = 0;
    __syncthreads();
    for (int e = lo + tid; e < hi; e += 256)
        atomicAdd(&hist[(pairs4[e] >> 20) & (BNODES - 1)], 1);
    __syncthreads();
    int v = hist[tid];
    cur[tid] = v;
    __syncthreads();
    for (int off = 1; off < BNODES; off <<= 1) {
        int x = (tid >= off) ? cur[tid - off] : 0;
        __syncthreads();
        cur[tid] += x;
        __syncthreads();
    }
    {
        int ex = cur[tid] - v;    // exclusive
        int node = node0 + tid;
        if (node < N) {
            rowstart[node] = lo + ex;
            dinv[node] = rsqrtf((float)(v + 1));   // +1 self-loop
        }
        cur[tid] = ex;            // local cursor
    }
    __syncthreads();
    for (int e = lo + tid; e < hi; e += 256) {
        int pr = pairs4[e];
        int p = atomicAdd(&cur[(pr >> 20) & (BNODES - 1)], 1);
        col[lo + p] = pr & 0xFFFFF;
    }
}

// ---------------- graph boundaries from sorted batch (no atomics) ----------------
__global__ void graph_bounds(const int* __restrict__ batch, int* __restrict__ nodestart,
                             int N, int G) {
    int i = blockIdx.x * blockDim.x + threadIdx.x;
    if (i >= N) return;
    int b = batch[i];
    int bp = (i == 0) ? -1 : batch[i - 1];
    for (int g = bp + 1; g <= b; ++g) nodestart[g] = i;
    if (i == N - 1) nodestart[G] = N;
}

// ---------------- segmented mean pool: one block per graph ----------------
__global__ void pool_mean(const float* __restrict__ h, const int* __restrict__ nodestart,
                          float* __restrict__ pooled, int G) {
    int g = blockIdx.x;
    int lo = nodestart[g], hi = nodestart[g + 1];
    int f = threadIdx.x & 63, w = threadIdx.x >> 6;
    float acc = 0.f;
    for (int n = lo + w; n < hi; n += 4) acc += h[(size_t)n * H + f];
    __shared__ float red[4][64];
    red[w][f] = acc;
    __syncthreads();
    if (w == 0) {
        float s = red[0][f] + red[1][f] + red[2][f] + red[3][f];
        float c = (float)(hi - lo);
        pooled[g * H + f] = s / fmaxf(c, 1.f);
    }
}

// ---------------- linear: N x 9 @ 9 x 64, output scaled by dinv ----------------
__global__ void lin_in(const float* __restrict__ x, const float* __restrict__ W,
                       const float* __restrict__ dinv, float* __restrict__ out, int N) {
    __shared__ float Ws[9 * H];
    __shared__ float xs[4 * 9];
    int tid = threadIdx.x;
    for (int idx = tid; idx < 9 * H; idx += 256) Ws[idx] = W[idx];
    int node0 = blockIdx.x * 4;
    for (int idx = tid; idx < 4 * 9; idx += 256) {
        int nl = idx / 9, k = idx % 9;
        int n = node0 + nl;
        xs[idx] = (n < N) ? x[n * 9 + k] : 0.f;
    }
    __syncthreads();
    int nl = tid >> 6, f = tid & 63;
    int n = node0 + nl;
    float acc = 0.f;
#pragma unroll
    for (int k = 0; k < 9; ++k) acc += xs[nl * 9 + k] * Ws[k * H + f];
    if (n < N) out[n * H + f] = acc * dinv[n];
}

// ---------------- linear: N x 64 @ 64 x 64 (16 nodes/block), scaled ----------------
__global__ void lin_h(const float* __restrict__ h, const float* __restrict__ W,
                      const float* __restrict__ dinv, float* __restrict__ out, int N) {
    __shared__ float Ws[H * H];     // 16 KB
    __shared__ float hs[16 * H];    // 4 KB
    int tid = threadIdx.x;
    int node0 = blockIdx.x * 16;
    for (int idx = tid; idx < H * H; idx += 256) Ws[idx] = W[idx];
    for (int idx = tid; idx < 16 * H; idx += 256) {
        int n = node0 + (idx >> 6);
        hs[idx] = (n < N) ? h[n * H + (idx & 63)] : 0.f;
    }
    __syncthreads();
    int nlb = tid >> 6, f = tid & 63;
    float a0 = 0.f, a1 = 0.f, a2 = 0.f, a3 = 0.f;
#pragma unroll 8
    for (int k = 0; k < H; ++k) {
        float w = Ws[k * H + f];
        a0 += hs[(nlb) * H + k] * w;
        a1 += hs[(nlb + 4) * H + k] * w;
        a2 += hs[(nlb + 8) * H + k] * w;
        a3 += hs[(nlb + 12) * H + k] * w;
    }
    int n;
    n = node0 + nlb;      if (n < N) out[n * H + f] = a0 * dinv[n];
    n = node0 + nlb + 4;  if (n < N) out[n * H + f] = a1 * dinv[n];
    n = node0 + nlb + 8;  if (n < N) out[n * H + f] = a2 * dinv[n];
    n = node0 + nlb + 12; if (n < N) out[n * H + f] = a3 * dinv[n];
}

// ---------------- aggregate: one wave per node, lane = feature ----------------
// hws is pre-scaled by dinv[src]; out = relu(bias + dinv[i]*(sum_nbr hws[src] + hws[i]))
__global__ void aggregate(const float* __restrict__ hws, const float* __restrict__ dinv,
                          const int* __restrict__ rowstart, const int* __restrict__ rowend,
                          const int* __restrict__ col, const float* __restrict__ bias,
                          float* __restrict__ out, int N) {
    int gtid = blockIdx.x * blockDim.x + threadIdx.x;
    int i = gtid >> 6;       // node = wave
    int f = threadIdx.x & 63;
    if (i >= N) return;
    float acc = hws[(size_t)i * H + f];  // self-loop term (dinv[i]*hw[i])
    int s = rowstart[i], e = rowend[i];
    for (int base = s; base < e; base += 64) {
        int cnt = e - base;
        if (cnt > 64) cnt = 64;
        int idx = 0;
        if (f < cnt) idx = col[base + f];   // coalesced 64-wide index load
        int j = 0;
        for (; j + 4 <= cnt; j += 4) {
            int s0 = __shfl(idx, j);     int s1 = __shfl(idx, j + 1);
            int s2 = __shfl(idx, j + 2); int s3 = __shfl(idx, j + 3);
            float v0 = hws[(size_t)s0 * H + f];
            float v1 = hws[(size_t)s1 * H + f];
            float v2 = hws[(size_t)s2 * H + f];
            float v3 = hws[(size_t)s3 * H + f];
            acc += v0 + v1 + v2 + v3;
        }
        for (; j < cnt; ++j) {
            int s0 = __shfl(idx, j);
            acc += hws[(size_t)s0 * H + f];
        }
    }
    out[(size_t)i * H + f] = fmaxf(bias[f] + dinv[i] * acc, 0.f);
}

// ---------------- final MLP: one wave per graph, shfl-based ----------------
__global__ void mlp(const float* __restrict__ pooled, const float* __restrict__ u,
                    const float* __restrict__ A1, const float* __restrict__ c1,
                    const float* __restrict__ A2, const float* __restrict__ c2,
                    const float* __restrict__ A3, const float* __restrict__ c3,
                    const float* __restrict__ A4, const float* __restrict__ c4,
                    const float* __restrict__ A5, const float* __restrict__ c5,
                    float* __restrict__ out, int G) {
    int wid = (blockIdx.x * blockDim.x + threadIdx.x) >> 6;  // wave = graph
    int lane = threadIdx.x & 63;
    if (wid >= G) return;
    int g = wid;

    float zreg = pooled[g * H + lane];          // lane k holds z[k], k<64
    float u0 = u[g * 4 + 0], u1 = u[g * 4 + 1], u2 = u[g * 4 + 2], u3 = u[g * 4 + 3];

    // layer 1: 68 -> 50
    float acc = (lane < 50) ? c1[lane] : 0.f;
#pragma unroll
    for (int k = 0; k < 64; ++k) {
        float zk = __shfl(zreg, k);
        float w = (lane < 50) ? A1[k * 50 + lane] : 0.f;
        acc = fmaf(zk, w, acc);
    }
    {
        float w;
        w = (lane < 50) ? A1[64 * 50 + lane] : 0.f; acc = fmaf(u0, w, acc);
        w = (lane < 50) ? A1[65 * 50 + lane] : 0.f; acc = fmaf(u1, w, acc);
        w = (lane < 50) ? A1[66 * 50 + lane] : 0.f; acc = fmaf(u2, w, acc);
        w = (lane < 50) ? A1[67 * 50 + lane] : 0.f; acc = fmaf(u3, w, acc);
    }
    float z1v = fmaxf(acc, 0.f);

    // layer 2: 50 -> 30
    acc = (lane < 30) ? c2[lane] : 0.f;
#pragma unroll
    for (int k = 0; k < 50; ++k) {
        float zk = __shfl(z1v, k);
        float w = (lane < 30) ? A2[k * 30 + lane] : 0.f;
        acc = fmaf(zk, w, acc);
    }
    float z2v = fmaxf(acc, 0.f);

    // layer 3: 30 -> 20
    acc = (lane < 20) ? c3[lane] : 0.f;
#pragma unroll
    for (int k = 0; k < 30; ++k) {
        float zk = __shfl(z2v, k);
        float w = (lane < 20) ? A3[k * 20 + lane] : 0.f;
        acc = fmaf(zk, w, acc);
    }
    float z3v = fmaxf(acc, 0.f);

    // layer 4: 20 -> 5
    acc = (lane < 5) ? c4[lane] : 0.f;
#pragma unroll
    for (int k = 0; k < 20; ++k) {
        float zk = __shfl(z3v, k);
        float w = (lane < 5) ? A4[k * 5 + lane] : 0.f;
        acc = fmaf(zk, w, acc);
    }
    float z4v = fmaxf(acc, 0.f);

    // layer 5: 5 -> 1
    acc = c5[0];
#pragma unroll
    for (int k = 0; k < 5; ++k) {
        float zk = __shfl(z4v, k);
        acc = fmaf(zk, A5[k], acc);
    }
    if (lane == 0) out[g] = fmaxf(acc, 0.f);
}

extern "C" void kernel_launch(void* const* d_in, const int* in_sizes, int n_in,
                              void* d_out, int out_size, void* d_ws, size_t ws_size,
                              hipStream_t stream) {
    const float* x     = (const float*)d_in[0];
    const int*   edge  = (const int*)d_in[1];
    const int*   batch = (const int*)d_in[2];
    const float* u     = (const float*)d_in[3];
    const float* W1 = (const float*)d_in[4];  const float* b1 = (const float*)d_in[5];
    const float* W2 = (const float*)d_in[6];  const float* b2 = (const float*)d_in[7];
    const float* W3 = (const float*)d_in[8];  const float* b3 = (const float*)d_in[9];
    const float* A1 = (const float*)d_in[10]; const float* c1 = (const float*)d_in[11];
    const float* A2 = (const float*)d_in[12]; const float* c2 = (const float*)d_in[13];
    const float* A3 = (const float*)d_in[14]; const float* c3 = (const float*)d_in[15];
    const float* A4 = (const float*)d_in[16]; const float* c4 = (const float*)d_in[17];
    const float* A5 = (const float*)d_in[18]; const float* c5 = (const float*)d_in[19];

    const int N = in_sizes[2];          // 100000
    const int E = in_sizes[1] / 2;      // 3200000
    const int G = in_sizes[3] / 4;      // 256
    const int* src = edge;
    const int* dst = edge + E;
    const int nbuck = (N + BNODES - 1) >> BNODE_SHIFT;   // 391

    // ---- workspace layout (pairs4 aliases hws: pairs4 dead before lin_in) ----
    char* ws = (char*)d_ws;
    size_t off = 0;
    auto alloc = [&](size_t bytes) -> void* {
        void* p = ws + off;
        off = (off + bytes + 255) & ~(size_t)255;
        return p;
    };
    float* hws       = (float*)alloc((size_t)N * H * 4);   // aliases pairs4 (E*4 <= N*H*4)
    float* h         = (float*)alloc((size_t)N * H * 4);
    int*   col       = (int*)alloc((size_t)E * 4);
    int*   rowstart  = (int*)alloc((size_t)(N + 1) * 4);
    float* dinv      = (float*)alloc((size_t)N * 4);
    int*   bcounts   = (int*)alloc((size_t)nbuck * 4);
    int*   boff      = (int*)alloc((size_t)(nbuck + 1) * 4);
    int*   bcur      = (int*)alloc((size_t)nbuck * 64);    // 64B-padded cursors
    int*   nodestart = (int*)alloc((size_t)(G + 1) * 4);
    float* pooled    = (float*)alloc((size_t)G * H * 4);
    int*   pairs4    = (int*)hws;

    const int nbN   = (N + 255) / 256;
    const int nbAgg = (N + 3) / 4;       // 4 waves/block, wave per node
    const int nchunks = (E + CHUNK - 1) / CHUNK;   // 261

    // ---- CSR build via block-local LDS sort ----
    zero_i32<<<(nbuck + 255) / 256, 256, 0, stream>>>(bcounts, nbuck);
    bucket_hist<<<256, 256, 0, stream>>>(dst, E, bcounts, nbuck);
    bucket_scan<<<1, 1024, 0, stream>>>(bcounts, boff, bcur, rowstart, nbuck, E, N);
    edge_sort_scatter<<<nchunks, 256, 0, stream>>>(src, dst, E, nbuck, bcur, pairs4);
    bucket_build<<<nbuck, 256, 0, stream>>>(pairs4, boff, col, rowstart, dinv, N);
    graph_bounds<<<nbN, 256, 0, stream>>>(batch, nodestart, N, G);

    // ---- conv1 ----
    lin_in<<<(N + 3) / 4, 256, 0, stream>>>(x, W1, dinv, hws, N);
    aggregate<<<nbAgg, 256, 0, stream>>>(hws, dinv, rowstart, rowstart + 1, col, b1, h, N);
    // ---- conv2 ----
    lin_h<<<(N + 15) / 16, 256, 0, stream>>>(h, W2, dinv, hws, N);
    aggregate<<<nbAgg, 256, 0, stream>>>(hws, dinv, rowstart, rowstart + 1, col, b2, h, N);
    // ---- conv3 ----
    lin_h<<<(N + 15) / 16, 256, 0, stream>>>(h, W3, dinv, hws, N);
    aggregate<<<nbAgg, 256, 0, stream>>>(hws, dinv, rowstart, rowstart + 1, col, b3, h, N);

    // ---- mean pool + final MLP ----
    pool_mean<<<G, 256, 0, stream>>>(h, nodestart, pooled, G);
    mlp<<<(G * 64 + 255) / 256, 256, 0, stream>>>(pooled, u, A1, c1, A2, c2, A3, c3,
                                                  A4, c4, A5, c5, (float*)d_out, G);
}

// Round 6
// 506.750 us; speedup vs baseline: 3.3108x; 1.1026x over previous
//
#include <hip/hip_runtime.h>

#define H 64
#define BNODE_SHIFT 8           // 256 nodes per bucket
#define BNODES 256
#define CHUNK 12288             // edges per sort block (48 per thread)
#define EPT 48

// ---------------- zero-fill ----------------
__global__ void zero_i32(int* p, int n) {
    int i = blockIdx.x * blockDim.x + threadIdx.x;
    if (i < n) p[i] = 0;
}

// ---------------- bucket histogram (LDS-local then merge) ----------------
__global__ void bucket_hist(const int* __restrict__ dst, int E,
                            int* __restrict__ bcounts, int nbuck) {
    __shared__ int hist[512];
    for (int i = threadIdx.x; i < nbuck; i += blockDim.x) hist[i] = 0;
    __syncthreads();
    for (int e = blockIdx.x * blockDim.x + threadIdx.x; e < E; e += gridDim.x * blockDim.x)
        atomicAdd(&hist[dst[e] >> BNODE_SHIFT], 1);
    __syncthreads();
    for (int i = threadIdx.x; i < nbuck; i += blockDim.x) {
        int v = hist[i];
        if (v) atomicAdd(&bcounts[i], v);
    }
}

// ---------------- bucket offsets scan (1 block) ----------------
__global__ void bucket_scan(const int* __restrict__ bcounts, int* __restrict__ boff,
                            int* __restrict__ bcur, int* __restrict__ rowstart,
                            int nbuck, int E, int N) {
    __shared__ int t[1024];
    int tid = threadIdx.x;
    int v = (tid < nbuck) ? bcounts[tid] : 0;
    t[tid] = v;
    __syncthreads();
    for (int off = 1; off < 1024; off <<= 1) {
        int x = (tid >= off) ? t[tid - off] : 0;
        __syncthreads();
        t[tid] += x;
        __syncthreads();
    }
    if (tid < nbuck) {
        int o = t[tid] - v;       // exclusive
        boff[tid] = o;
        bcur[tid * 16] = o;       // 64B-padded cursor
    }
    if (tid == 0) { boff[nbuck] = E; rowstart[N] = E; }
}

// ---------------- block-local LDS sort + coalesced flush ----------------
// pack: src (bits 0..19) | local_dst (bits 20..27)
__global__ void edge_sort_scatter(const int* __restrict__ src, const int* __restrict__ dst,
                                  int E, int nbuck,
                                  int* __restrict__ bcur, int* __restrict__ pairs4) {
    __shared__ int hist[392];
    __shared__ int bstart[393];
    __shared__ int cur[392];
    __shared__ int gbase[392];
    __shared__ int wsum[256];
    __shared__ int packed[CHUNK];   // 48 KB

    int t = threadIdx.x;
    int chunkBase = blockIdx.x * CHUNK;

    // phase 1: local histogram
    for (int i = t; i < nbuck; i += 256) hist[i] = 0;
    __syncthreads();
    for (int k = 0; k < EPT; ++k) {
        int e = chunkBase + t + k * 256;
        if (e < E) atomicAdd(&hist[dst[e] >> BNODE_SHIFT], 1);
    }
    __syncthreads();

    // phase 2: exclusive scan of hist (2 items/thread covers <=512 buckets)
    int a0 = (2 * t < nbuck) ? hist[2 * t] : 0;
    int a1 = (2 * t + 1 < nbuck) ? hist[2 * t + 1] : 0;
    int s2 = a0 + a1;
    wsum[t] = s2;
    __syncthreads();
    for (int off = 1; off < 256; off <<= 1) {
        int x = (t >= off) ? wsum[t - off] : 0;
        __syncthreads();
        wsum[t] += x;
        __syncthreads();
    }
    int base = wsum[t] - s2;        // exclusive
    if (2 * t < nbuck)     bstart[2 * t] = base;
    if (2 * t + 1 < nbuck) bstart[2 * t + 1] = base + a0;
    if (t == 255) bstart[nbuck] = wsum[255];   // chunk edge count
    __syncthreads();

    // phase 2b: reserve global spans; init local cursors
    for (int b = t; b < nbuck; b += 256) {
        int cnt = bstart[b + 1] - bstart[b];
        gbase[b] = cnt ? atomicAdd(&bcur[b * 16], cnt) : 0;
        cur[b] = bstart[b];
    }
    __syncthreads();

    // phase 3: place edges sorted into LDS (re-read edges; L2-hot)
    for (int k = 0; k < EPT; ++k) {
        int e = chunkBase + t + k * 256;
        if (e < E) {
            int d = dst[e];
            int b = d >> BNODE_SHIFT;
            int pos = atomicAdd(&cur[b], 1);
            packed[pos] = src[e] | ((d & (BNODES - 1)) << 20);
        }
    }
    __syncthreads();

    // phase 4: coalesced flush, one bucket run per wave
    int w = t >> 6, lane = t & 63;
    for (int b = w; b < nbuck; b += 4) {
        int lb = bstart[b], le = bstart[b + 1];
        int gb = gbase[b];
        for (int j = lb + lane; j < le; j += 64)
            pairs4[gb + (j - lb)] = packed[j];
    }
}

// ---------------- exact CSR within each bucket (LDS atomics) ----------------
__global__ void bucket_build(const int* __restrict__ pairs4, const int* __restrict__ boff,
                             int* __restrict__ col, int* __restrict__ rowstart,
                             float* __restrict__ dinv, int N) {
    __shared__ int hist[BNODES];
    __shared__ int cur[BNODES];
    int b = blockIdx.x;
    int lo = boff[b], hi = boff[b + 1];
    int node0 = b << BNODE_SHIFT;
    int tid = threadIdx.x;
    hist[tid] = 0;
    __syncthreads();
    for (int e = lo + tid; e < hi; e += 256)
        atomicAdd(&hist[(pairs4[e] >> 20) & (BNODES - 1)], 1);
    __syncthreads();
    int v = hist[tid];
    cur[tid] = v;
    __syncthreads();
    for (int off = 1; off < BNODES; off <<= 1) {
        int x = (tid >= off) ? cur[tid - off] : 0;
        __syncthreads();
        cur[tid] += x;
        __syncthreads();
    }
    {
        int ex = cur[tid] - v;    // exclusive
        int node = node0 + tid;
        if (node < N) {
            rowstart[node] = lo + ex;
            dinv[node] = rsqrtf((float)(v + 1));   // +1 self-loop
        }
        cur[tid] = ex;            // local cursor
    }
    __syncthreads();
    for (int e = lo + tid; e < hi; e += 256) {
        int pr = pairs4[e];
        int p = atomicAdd(&cur[(pr >> 20) & (BNODES - 1)], 1);
        col[lo + p] = pr & 0xFFFFF;
    }
}

// ---------------- graph boundaries from sorted batch (no atomics) ----------------
__global__ void graph_bounds(const int* __restrict__ batch, int* __restrict__ nodestart,
                             int N, int G) {
    int i = blockIdx.x * blockDim.x + threadIdx.x;
    if (i >= N) return;
    int b = batch[i];
    int bp = (i == 0) ? -1 : batch[i - 1];
    for (int g = bp + 1; g <= b; ++g) nodestart[g] = i;
    if (i == N - 1) nodestart[G] = N;
}

// ---------------- segmented mean pool: one block per graph ----------------
__global__ void pool_mean(const float* __restrict__ h, const int* __restrict__ nodestart,
                          float* __restrict__ pooled, int G) {
    int g = blockIdx.x;
    int lo = nodestart[g], hi = nodestart[g + 1];
    int f = threadIdx.x & 63, w = threadIdx.x >> 6;
    float acc = 0.f;
    for (int n = lo + w; n < hi; n += 4) acc += h[(size_t)n * H + f];
    __shared__ float red[4][64];
    red[w][f] = acc;
    __syncthreads();
    if (w == 0) {
        float s = red[0][f] + red[1][f] + red[2][f] + red[3][f];
        float c = (float)(hi - lo);
        pooled[g * H + f] = s / fmaxf(c, 1.f);
    }
}

// ---------------- prep: pad x to 16 floats/row, pre-scale by dinv ----------------
__global__ void prep_x16(const float* __restrict__ x, const float* __restrict__ dinv,
                         float* __restrict__ xp, int N) {
    int i = blockIdx.x * blockDim.x + threadIdx.x;
    if (i >= N * 16) return;
    int n = i >> 4, k = i & 15;
    xp[i] = (k < 9) ? x[n * 9 + k] * dinv[n] : 0.f;
}

// ---------------- conv1 fused: agg = dinv_i*(sum xp[src] + xp[i]); out = relu(agg@W1 + b1)
// wave per node; lanes: f16 = lane&15 (feature), grp = lane>>4 (4 edges in parallel)
__global__ void conv1_fused(const float* __restrict__ xp, const float* __restrict__ dinv,
                            const int* __restrict__ rowstart, const int* __restrict__ rowend,
                            const int* __restrict__ col, const float* __restrict__ W1,
                            const float* __restrict__ b1, float* __restrict__ out, int N) {
    int gtid = blockIdx.x * blockDim.x + threadIdx.x;
    int i = gtid >> 6;
    int lane = threadIdx.x & 63;
    int f16 = lane & 15, grp = lane >> 4;
    if (i >= N) return;
    float di = dinv[i];
    float sv = xp[(size_t)i * 16 + f16];     // self (already dinv_i-scaled)
    float acc = 0.f;
    int s = rowstart[i], e = rowend[i];
    for (int base = s; base < e; base += 64) {
        int cnt = e - base;
        if (cnt > 64) cnt = 64;
        int idx = 0;
        if (lane < cnt) idx = col[base + lane];
        for (int j = 0; j < cnt; j += 8) {
            int j0 = j + grp, j1 = j + 4 + grp;
            int s0 = __shfl(idx, j0);
            int s1 = __shfl(idx, j1 & 63);
            float v0 = (j0 < cnt) ? xp[(size_t)s0 * 16 + f16] : 0.f;
            float v1 = (j1 < cnt) ? xp[(size_t)s1 * 16 + f16] : 0.f;
            acc += v0 + v1;
        }
    }
    // reduce 4 edge-groups
    acc += __shfl_xor(acc, 16);
    acc += __shfl_xor(acc, 32);
    float aggf = di * (acc + sv);            // lane k (k<9 within group) holds agg[k]

    // out[lane] = relu(b1[lane] + sum_k agg[k]*W1[k*64+lane])
    float o = b1[lane];
#pragma unroll
    for (int k = 0; k < 9; ++k) {
        float ak = __shfl(aggf, k);          // readlane (k < 16)
        o = fmaf(ak, W1[k * H + lane], o);
    }
    out[(size_t)i * H + lane] = fmaxf(o, 0.f);
}

// ---------------- linear: N x 64 @ 64 x 64 (16 nodes/block), scaled by dinv ----------------
__global__ void lin_h(const float* __restrict__ h, const float* __restrict__ W,
                      const float* __restrict__ dinv, float* __restrict__ out, int N) {
    __shared__ float Ws[H * H];     // 16 KB
    __shared__ float hs[16 * H];    // 4 KB
    int tid = threadIdx.x;
    int node0 = blockIdx.x * 16;
    for (int idx = tid; idx < H * H; idx += 256) Ws[idx] = W[idx];
    for (int idx = tid; idx < 16 * H; idx += 256) {
        int n = node0 + (idx >> 6);
        hs[idx] = (n < N) ? h[n * H + (idx & 63)] : 0.f;
    }
    __syncthreads();
    int nlb = tid >> 6, f = tid & 63;
    float a0 = 0.f, a1 = 0.f, a2 = 0.f, a3 = 0.f;
#pragma unroll 8
    for (int k = 0; k < H; ++k) {
        float w = Ws[k * H + f];
        a0 += hs[(nlb) * H + k] * w;
        a1 += hs[(nlb + 4) * H + k] * w;
        a2 += hs[(nlb + 8) * H + k] * w;
        a3 += hs[(nlb + 12) * H + k] * w;
    }
    int n;
    n = node0 + nlb;      if (n < N) out[n * H + f] = a0 * dinv[n];
    n = node0 + nlb + 4;  if (n < N) out[n * H + f] = a1 * dinv[n];
    n = node0 + nlb + 8;  if (n < N) out[n * H + f] = a2 * dinv[n];
    n = node0 + nlb + 12; if (n < N) out[n * H + f] = a3 * dinv[n];
}

// ---------------- aggregate (float2 lanes): wave per node ----------------
// lanes: f2 = lane&31 (feature pair), grp = lane>>5 (2 edges in parallel)
// hws pre-scaled by dinv[src]; out = relu(bias + dinv_i*(sum hws[src] + hws[i]))
__global__ void aggregate2(const float* __restrict__ hws, const float* __restrict__ dinv,
                           const int* __restrict__ rowstart, const int* __restrict__ rowend,
                           const int* __restrict__ col, const float* __restrict__ bias,
                           float* __restrict__ out, int N) {
    int gtid = blockIdx.x * blockDim.x + threadIdx.x;
    int i = gtid >> 6;
    int lane = threadIdx.x & 63;
    int f2 = lane & 31, grp = lane >> 5;
    if (i >= N) return;
    const float2* h2 = (const float2*)hws;
    float di = dinv[i];
    float2 sv = h2[(size_t)i * 32 + f2];
    float ax = 0.f, ay = 0.f;
    int s = rowstart[i], e = rowend[i];
    for (int base = s; base < e; base += 64) {
        int cnt = e - base;
        if (cnt > 64) cnt = 64;
        int idx = 0;
        if (lane < cnt) idx = col[base + lane];
        for (int j = 0; j < cnt; j += 8) {
            int ja = j + grp, jb = ja + 2, jc = ja + 4, jd = ja + 6;
            int sa = __shfl(idx, ja);
            int sb = __shfl(idx, jb & 63);
            int sc = __shfl(idx, jc & 63);
            int sd = __shfl(idx, jd & 63);
            if (ja < cnt) { float2 v = h2[(size_t)sa * 32 + f2]; ax += v.x; ay += v.y; }
            if (jb < cnt) { float2 v = h2[(size_t)sb * 32 + f2]; ax += v.x; ay += v.y; }
            if (jc < cnt) { float2 v = h2[(size_t)sc * 32 + f2]; ax += v.x; ay += v.y; }
            if (jd < cnt) { float2 v = h2[(size_t)sd * 32 + f2]; ax += v.x; ay += v.y; }
        }
    }
    // reduce the two edge-groups
    ax += __shfl_xor(ax, 32);
    ay += __shfl_xor(ay, 32);
    if (grp == 0) {
        const float2* b2p = (const float2*)bias;
        float2 bb = b2p[f2];
        float2 r;
        r.x = fmaxf(bb.x + di * (ax + sv.x), 0.f);
        r.y = fmaxf(bb.y + di * (ay + sv.y), 0.f);
        ((float2*)out)[(size_t)i * 32 + f2] = r;
    }
}

// ---------------- final MLP: one wave per graph, shfl-based ----------------
__global__ void mlp(const float* __restrict__ pooled, const float* __restrict__ u,
                    const float* __restrict__ A1, const float* __restrict__ c1,
                    const float* __restrict__ A2, const float* __restrict__ c2,
                    const float* __restrict__ A3, const float* __restrict__ c3,
                    const float* __restrict__ A4, const float* __restrict__ c4,
                    const float* __restrict__ A5, const float* __restrict__ c5,
                    float* __restrict__ out, int G) {
    int wid = (blockIdx.x * blockDim.x + threadIdx.x) >> 6;  // wave = graph
    int lane = threadIdx.x & 63;
    if (wid >= G) return;
    int g = wid;

    float zreg = pooled[g * H + lane];          // lane k holds z[k], k<64
    float u0 = u[g * 4 + 0], u1 = u[g * 4 + 1], u2 = u[g * 4 + 2], u3 = u[g * 4 + 3];

    // layer 1: 68 -> 50
    float acc = (lane < 50) ? c1[lane] : 0.f;
#pragma unroll
    for (int k = 0; k < 64; ++k) {
        float zk = __shfl(zreg, k);
        float w = (lane < 50) ? A1[k * 50 + lane] : 0.f;
        acc = fmaf(zk, w, acc);
    }
    {
        float w;
        w = (lane < 50) ? A1[64 * 50 + lane] : 0.f; acc = fmaf(u0, w, acc);
        w = (lane < 50) ? A1[65 * 50 + lane] : 0.f; acc = fmaf(u1, w, acc);
        w = (lane < 50) ? A1[66 * 50 + lane] : 0.f; acc = fmaf(u2, w, acc);
        w = (lane < 50) ? A1[67 * 50 + lane] : 0.f; acc = fmaf(u3, w, acc);
    }
    float z1v = fmaxf(acc, 0.f);

    // layer 2: 50 -> 30
    acc = (lane < 30) ? c2[lane] : 0.f;
#pragma unroll
    for (int k = 0; k < 50; ++k) {
        float zk = __shfl(z1v, k);
        float w = (lane < 30) ? A2[k * 30 + lane] : 0.f;
        acc = fmaf(zk, w, acc);
    }
    float z2v = fmaxf(acc, 0.f);

    // layer 3: 30 -> 20
    acc = (lane < 20) ? c3[lane] : 0.f;
#pragma unroll
    for (int k = 0; k < 30; ++k) {
        float zk = __shfl(z2v, k);
        float w = (lane < 20) ? A3[k * 20 + lane] : 0.f;
        acc = fmaf(zk, w, acc);
    }
    float z3v = fmaxf(acc, 0.f);

    // layer 4: 20 -> 5
    acc = (lane < 5) ? c4[lane] : 0.f;
#pragma unroll
    for (int k = 0; k < 20; ++k) {
        float zk = __shfl(z3v, k);
        float w = (lane < 5) ? A4[k * 5 + lane] : 0.f;
        acc = fmaf(zk, w, acc);
    }
    float z4v = fmaxf(acc, 0.f);

    // layer 5: 5 -> 1
    acc = c5[0];
#pragma unroll
    for (int k = 0; k < 5; ++k) {
        float zk = __shfl(z4v, k);
        acc = fmaf(zk, A5[k], acc);
    }
    if (lane == 0) out[g] = fmaxf(acc, 0.f);
}

extern "C" void kernel_launch(void* const* d_in, const int* in_sizes, int n_in,
                              void* d_out, int out_size, void* d_ws, size_t ws_size,
                              hipStream_t stream) {
    const float* x     = (const float*)d_in[0];
    const int*   edge  = (const int*)d_in[1];
    const int*   batch = (const int*)d_in[2];
    const float* u     = (const float*)d_in[3];
    const float* W1 = (const float*)d_in[4];  const float* b1 = (const float*)d_in[5];
    const float* W2 = (const float*)d_in[6];  const float* b2 = (const float*)d_in[7];
    const float* W3 = (const float*)d_in[8];  const float* b3 = (const float*)d_in[9];
    const float* A1 = (const float*)d_in[10]; const float* c1 = (const float*)d_in[11];
    const float* A2 = (const float*)d_in[12]; const float* c2 = (const float*)d_in[13];
    const float* A3 = (const float*)d_in[14]; const float* c3 = (const float*)d_in[15];
    const float* A4 = (const float*)d_in[16]; const float* c4 = (const float*)d_in[17];
    const float* A5 = (const float*)d_in[18]; const float* c5 = (const float*)d_in[19];

    const int N = in_sizes[2];          // 100000
    const int E = in_sizes[1] / 2;      // 3200000
    const int G = in_sizes[3] / 4;      // 256
    const int* src = edge;
    const int* dst = edge + E;
    const int nbuck = (N + BNODES - 1) >> BNODE_SHIFT;   // 391

    // ---- workspace layout (pairs4 aliases hws: pairs4 dead before lin_h writes) ----
    char* ws = (char*)d_ws;
    size_t off = 0;
    auto alloc = [&](size_t bytes) -> void* {
        void* p = ws + off;
        off = (off + bytes + 255) & ~(size_t)255;
        return p;
    };
    float* hws       = (float*)alloc((size_t)N * H * 4);   // aliases pairs4 (E*4 <= N*H*4)
    float* h         = (float*)alloc((size_t)N * H * 4);
    int*   col       = (int*)alloc((size_t)E * 4);
    float* xp        = (float*)alloc((size_t)N * 16 * 4);
    int*   rowstart  = (int*)alloc((size_t)(N + 1) * 4);
    float* dinv      = (float*)alloc((size_t)N * 4);
    int*   bcounts   = (int*)alloc((size_t)nbuck * 4);
    int*   boff      = (int*)alloc((size_t)(nbuck + 1) * 4);
    int*   bcur      = (int*)alloc((size_t)nbuck * 64);    // 64B-padded cursors
    int*   nodestart = (int*)alloc((size_t)(G + 1) * 4);
    float* pooled    = (float*)alloc((size_t)G * H * 4);
    int*   pairs4    = (int*)hws;

    const int nbN   = (N + 255) / 256;
    const int nbAgg = (N + 3) / 4;       // 4 waves/block, wave per node
    const int nchunks = (E + CHUNK - 1) / CHUNK;

    // ---- CSR build via block-local LDS sort ----
    zero_i32<<<(nbuck + 255) / 256, 256, 0, stream>>>(bcounts, nbuck);
    bucket_hist<<<256, 256, 0, stream>>>(dst, E, bcounts, nbuck);
    bucket_scan<<<1, 1024, 0, stream>>>(bcounts, boff, bcur, rowstart, nbuck, E, N);
    edge_sort_scatter<<<nchunks, 256, 0, stream>>>(src, dst, E, nbuck, bcur, pairs4);
    bucket_build<<<nbuck, 256, 0, stream>>>(pairs4, boff, col, rowstart, dinv, N);
    graph_bounds<<<nbN, 256, 0, stream>>>(batch, nodestart, N, G);

    // ---- conv1 (fused: aggregate 9-wide raw x, then W1) ----
    prep_x16<<<(N * 16 + 255) / 256, 256, 0, stream>>>(x, dinv, xp, N);
    conv1_fused<<<nbAgg, 256, 0, stream>>>(xp, dinv, rowstart, rowstart + 1, col, W1, b1, h, N);
    // ---- conv2 ----
    lin_h<<<(N + 15) / 16, 256, 0, stream>>>(h, W2, dinv, hws, N);
    aggregate2<<<nbAgg, 256, 0, stream>>>(hws, dinv, rowstart, rowstart + 1, col, b2, h, N);
    // ---- conv3 ----
    lin_h<<<(N + 15) / 16, 256, 0, stream>>>(h, W3, dinv, hws, N);
    aggregate2<<<nbAgg, 256, 0, stream>>>(hws, dinv, rowstart, rowstart + 1, col, b3, h, N);

    // ---- mean pool + final MLP ----
    pool_mean<<<G, 256, 0, stream>>>(h, nodestart, pooled, G);
    mlp<<<(G * 64 + 255) / 256, 256, 0, stream>>>(pooled, u, A1, c1, A2, c2, A3, c3,
                                                  A4, c4, A5, c5, (float*)d_out, G);
}

// Round 7
// 426.800 us; speedup vs baseline: 3.9310x; 1.1873x over previous
//
#include <hip/hip_runtime.h>

#define H 64
#define BNODE_SHIFT 8           // 256 nodes per bucket
#define BNODES 256
#define CHUNK 12288             // edges per sort block (48 per thread)
#define EPT 48

// bf16 helpers: bf16->fp32 is exact (bit shift); fp32->bf16 round-to-nearest-even
static __device__ __forceinline__ float b2f(ushort b) {
    return __uint_as_float(((unsigned int)b) << 16);
}
static __device__ __forceinline__ ushort f2b(float f) {
    unsigned int u = __float_as_uint(f);
    return (ushort)((u + 0x7FFF + ((u >> 16) & 1)) >> 16);
}

// ---------------- zero-fill ----------------
__global__ void zero_i32(int* p, int n) {
    int i = blockIdx.x * blockDim.x + threadIdx.x;
    if (i < n) p[i] = 0;
}

// ---------------- bucket histogram (LDS-local then merge) ----------------
__global__ void bucket_hist(const int* __restrict__ dst, int E,
                            int* __restrict__ bcounts, int nbuck) {
    __shared__ int hist[512];
    for (int i = threadIdx.x; i < nbuck; i += blockDim.x) hist[i] = 0;
    __syncthreads();
    for (int e = blockIdx.x * blockDim.x + threadIdx.x; e < E; e += gridDim.x * blockDim.x)
        atomicAdd(&hist[dst[e] >> BNODE_SHIFT], 1);
    __syncthreads();
    for (int i = threadIdx.x; i < nbuck; i += blockDim.x) {
        int v = hist[i];
        if (v) atomicAdd(&bcounts[i], v);
    }
}

// ---------------- bucket offsets scan (1 block) ----------------
__global__ void bucket_scan(const int* __restrict__ bcounts, int* __restrict__ boff,
                            int* __restrict__ bcur, int* __restrict__ rowstart,
                            int nbuck, int E, int N) {
    __shared__ int t[1024];
    int tid = threadIdx.x;
    int v = (tid < nbuck) ? bcounts[tid] : 0;
    t[tid] = v;
    __syncthreads();
    for (int off = 1; off < 1024; off <<= 1) {
        int x = (tid >= off) ? t[tid - off] : 0;
        __syncthreads();
        t[tid] += x;
        __syncthreads();
    }
    if (tid < nbuck) {
        int o = t[tid] - v;       // exclusive
        boff[tid] = o;
        bcur[tid * 16] = o;       // 64B-padded cursor
    }
    if (tid == 0) { boff[nbuck] = E; rowstart[N] = E; }
}

// ---------------- block-local LDS sort + coalesced flush ----------------
// pack: src (bits 0..19) | local_dst (bits 20..27)
__global__ void edge_sort_scatter(const int* __restrict__ src, const int* __restrict__ dst,
                                  int E, int nbuck,
                                  int* __restrict__ bcur, int* __restrict__ pairs4) {
    __shared__ int hist[392];
    __shared__ int bstart[393];
    __shared__ int cur[392];
    __shared__ int gbase[392];
    __shared__ int wsum[256];
    __shared__ int packed[CHUNK];   // 48 KB

    int t = threadIdx.x;
    int chunkBase = blockIdx.x * CHUNK;

    // phase 1: local histogram
    for (int i = t; i < nbuck; i += 256) hist[i] = 0;
    __syncthreads();
    for (int k = 0; k < EPT; ++k) {
        int e = chunkBase + t + k * 256;
        if (e < E) atomicAdd(&hist[dst[e] >> BNODE_SHIFT], 1);
    }
    __syncthreads();

    // phase 2: exclusive scan of hist
    int a0 = (2 * t < nbuck) ? hist[2 * t] : 0;
    int a1 = (2 * t + 1 < nbuck) ? hist[2 * t + 1] : 0;
    int s2 = a0 + a1;
    wsum[t] = s2;
    __syncthreads();
    for (int off = 1; off < 256; off <<= 1) {
        int x = (t >= off) ? wsum[t - off] : 0;
        __syncthreads();
        wsum[t] += x;
        __syncthreads();
    }
    int base = wsum[t] - s2;        // exclusive
    if (2 * t < nbuck)     bstart[2 * t] = base;
    if (2 * t + 1 < nbuck) bstart[2 * t + 1] = base + a0;
    if (t == 255) bstart[nbuck] = wsum[255];
    __syncthreads();

    // phase 2b: reserve global spans; init local cursors
    for (int b = t; b < nbuck; b += 256) {
        int cnt = bstart[b + 1] - bstart[b];
        gbase[b] = cnt ? atomicAdd(&bcur[b * 16], cnt) : 0;
        cur[b] = bstart[b];
    }
    __syncthreads();

    // phase 3: place edges sorted into LDS
    for (int k = 0; k < EPT; ++k) {
        int e = chunkBase + t + k * 256;
        if (e < E) {
            int d = dst[e];
            int b = d >> BNODE_SHIFT;
            int pos = atomicAdd(&cur[b], 1);
            packed[pos] = src[e] | ((d & (BNODES - 1)) << 20);
        }
    }
    __syncthreads();

    // phase 4: coalesced flush, one bucket run per wave
    int w = t >> 6, lane = t & 63;
    for (int b = w; b < nbuck; b += 4) {
        int lb = bstart[b], le = bstart[b + 1];
        int gb = gbase[b];
        for (int j = lb + lane; j < le; j += 64)
            pairs4[gb + (j - lb)] = packed[j];
    }
}

// ---------------- exact CSR within each bucket (LDS atomics) ----------------
__global__ void bucket_build(const int* __restrict__ pairs4, const int* __restrict__ boff,
                             int* __restrict__ col, int* __restrict__ rowstart,
                             float* __restrict__ dinv, int N) {
    __shared__ int hist[BNODES];
    __shared__ int cur[BNODES];
    int b = blockIdx.x;
    int lo = boff[b], hi = boff[b + 1];
    int node0 = b << BNODE_SHIFT;
    int tid = threadIdx.x;
    hist[tid] = 0;
    __syncthreads();
    for (int e = lo + tid; e < hi; e += 256)
        atomicAdd(&hist[(pairs4[e] >> 20) & (BNODES - 1)], 1);
    __syncthreads();
    int v = hist[tid];
    cur[tid] = v;
    __syncthreads();
    for (int off = 1; off < BNODES; off <<= 1) {
        int x = (tid >= off) ? cur[tid - off] : 0;
        __syncthreads();
        cur[tid] += x;
        __syncthreads();
    }
    {
        int ex = cur[tid] - v;    // exclusive
        int node = node0 + tid;
        if (node < N) {
            rowstart[node] = lo + ex;
            dinv[node] = rsqrtf((float)(v + 1));   // +1 self-loop
        }
        cur[tid] = ex;            // local cursor
    }
    __syncthreads();
    for (int e = lo + tid; e < hi; e += 256) {
        int pr = pairs4[e];
        int p = atomicAdd(&cur[(pr >> 20) & (BNODES - 1)], 1);
        col[lo + p] = pr & 0xFFFFF;
    }
}

// ---------------- graph boundaries from sorted batch (no atomics) ----------------
__global__ void graph_bounds(const int* __restrict__ batch, int* __restrict__ nodestart,
                             int N, int G) {
    int i = blockIdx.x * blockDim.x + threadIdx.x;
    if (i >= N) return;
    int b = batch[i];
    int bp = (i == 0) ? -1 : batch[i - 1];
    for (int g = bp + 1; g <= b; ++g) nodestart[g] = i;
    if (i == N - 1) nodestart[G] = N;
}

// ---------------- segmented mean pool: one block per graph ----------------
__global__ void pool_mean(const float* __restrict__ h, const int* __restrict__ nodestart,
                          float* __restrict__ pooled, int G) {
    int g = blockIdx.x;
    int lo = nodestart[g], hi = nodestart[g + 1];
    int f = threadIdx.x & 63, w = threadIdx.x >> 6;
    float acc = 0.f;
    for (int n = lo + w; n < hi; n += 4) acc += h[(size_t)n * H + f];
    __shared__ float red[4][64];
    red[w][f] = acc;
    __syncthreads();
    if (w == 0) {
        float s = red[0][f] + red[1][f] + red[2][f] + red[3][f];
        float c = (float)(hi - lo);
        pooled[g * H + f] = s / fmaxf(c, 1.f);
    }
}

// ---------------- prep: pad x to 16 bf16/row (32B), pre-scaled by dinv ----------------
__global__ void prep_xb(const float* __restrict__ x, const float* __restrict__ dinv,
                        ushort* __restrict__ xb, int N) {
    int i = blockIdx.x * blockDim.x + threadIdx.x;
    if (i >= N * 16) return;
    int n = i >> 4, k = i & 15;
    xb[i] = (k < 9) ? f2b(x[n * 9 + k] * dinv[n]) : (ushort)0;
}

// ---------------- conv1 fused: agg = dinv_i*(sum xb[src] + xb[i]); out = relu(agg@W1+b1)
// wave per node; lanes: f16 = lane&15 (feature), grp = lane>>4 (4 edges in parallel)
__global__ void conv1_fused(const ushort* __restrict__ xb, const float* __restrict__ dinv,
                            const int* __restrict__ rowstart, const int* __restrict__ rowend,
                            const int* __restrict__ col, const float* __restrict__ W1,
                            const float* __restrict__ b1, float* __restrict__ out, int N) {
    int gtid = blockIdx.x * blockDim.x + threadIdx.x;
    int i = gtid >> 6;
    int lane = threadIdx.x & 63;
    int f16 = lane & 15, grp = lane >> 4;
    if (i >= N) return;
    float di = dinv[i];
    float sv = b2f(xb[(size_t)i * 16 + f16]);   // self (already dinv_i-scaled)
    float acc = 0.f;
    int s = rowstart[i], e = rowend[i];
    for (int base = s; base < e; base += 64) {
        int cnt = e - base;
        if (cnt > 64) cnt = 64;
        int idx = 0;
        if (lane < cnt) idx = col[base + lane];
        for (int j = 0; j < cnt; j += 8) {
            int j0 = j + grp, j1 = j + 4 + grp;
            int s0 = __shfl(idx, j0);
            int s1 = __shfl(idx, j1 & 63);
            float v0 = (j0 < cnt) ? b2f(xb[(size_t)s0 * 16 + f16]) : 0.f;
            float v1 = (j1 < cnt) ? b2f(xb[(size_t)s1 * 16 + f16]) : 0.f;
            acc += v0 + v1;
        }
    }
    // reduce 4 edge-groups
    acc += __shfl_xor(acc, 16);
    acc += __shfl_xor(acc, 32);
    float aggf = di * (acc + sv);            // lane k (k<9) holds agg[k]

    float o = b1[lane];
#pragma unroll
    for (int k = 0; k < 9; ++k) {
        float ak = __shfl(aggf, k);
        o = fmaf(ak, W1[k * H + lane], o);
    }
    out[(size_t)i * H + lane] = fmaxf(o, 0.f);
}

// ---------------- linear: N x 64 @ 64 x 64 (16 nodes/block), scaled, bf16 out ----------------
__global__ void lin_h(const float* __restrict__ h, const float* __restrict__ W,
                      const float* __restrict__ dinv, ushort* __restrict__ out, int N) {
    __shared__ float Ws[H * H];     // 16 KB
    __shared__ float hs[16 * H];    // 4 KB
    int tid = threadIdx.x;
    int node0 = blockIdx.x * 16;
    for (int idx = tid; idx < H * H; idx += 256) Ws[idx] = W[idx];
    for (int idx = tid; idx < 16 * H; idx += 256) {
        int n = node0 + (idx >> 6);
        hs[idx] = (n < N) ? h[n * H + (idx & 63)] : 0.f;
    }
    __syncthreads();
    int nlb = tid >> 6, f = tid & 63;
    float a0 = 0.f, a1 = 0.f, a2 = 0.f, a3 = 0.f;
#pragma unroll 8
    for (int k = 0; k < H; ++k) {
        float w = Ws[k * H + f];
        a0 += hs[(nlb) * H + k] * w;
        a1 += hs[(nlb + 4) * H + k] * w;
        a2 += hs[(nlb + 8) * H + k] * w;
        a3 += hs[(nlb + 12) * H + k] * w;
    }
    int n;
    n = node0 + nlb;      if (n < N) out[n * H + f] = f2b(a0 * dinv[n]);
    n = node0 + nlb + 4;  if (n < N) out[n * H + f] = f2b(a1 * dinv[n]);
    n = node0 + nlb + 8;  if (n < N) out[n * H + f] = f2b(a2 * dinv[n]);
    n = node0 + nlb + 12; if (n < N) out[n * H + f] = f2b(a3 * dinv[n]);
}

// ---------------- aggregate (bf16 gather): one wave per node, lane = feature ----------------
// hb pre-scaled by dinv[src]; out = relu(bias + dinv_i*(sum hb[src] + hb[i]))
__global__ void aggregate_b(const ushort* __restrict__ hb, const float* __restrict__ dinv,
                            const int* __restrict__ rowstart, const int* __restrict__ rowend,
                            const int* __restrict__ col, const float* __restrict__ bias,
                            float* __restrict__ out, int N) {
    int gtid = blockIdx.x * blockDim.x + threadIdx.x;
    int i = gtid >> 6;       // node = wave
    int f = threadIdx.x & 63;
    if (i >= N) return;
    float acc = b2f(hb[(size_t)i * H + f]);  // self-loop term (dinv_i*hw[i])
    int s = rowstart[i], e = rowend[i];
    for (int base = s; base < e; base += 64) {
        int cnt = e - base;
        if (cnt > 64) cnt = 64;
        int idx = 0;
        if (f < cnt) idx = col[base + f];   // coalesced 64-wide index load
        int j = 0;
        for (; j + 4 <= cnt; j += 4) {
            int s0 = __shfl(idx, j);     int s1 = __shfl(idx, j + 1);
            int s2 = __shfl(idx, j + 2); int s3 = __shfl(idx, j + 3);
            float v0 = b2f(hb[(size_t)s0 * H + f]);
            float v1 = b2f(hb[(size_t)s1 * H + f]);
            float v2 = b2f(hb[(size_t)s2 * H + f]);
            float v3 = b2f(hb[(size_t)s3 * H + f]);
            acc += (v0 + v1) + (v2 + v3);
        }
        for (; j < cnt; ++j) {
            int s0 = __shfl(idx, j);
            acc += b2f(hb[(size_t)s0 * H + f]);
        }
    }
    out[(size_t)i * H + f] = fmaxf(bias[f] + dinv[i] * acc, 0.f);
}

// ---------------- final MLP: one wave per graph, shfl-based ----------------
__global__ void mlp(const float* __restrict__ pooled, const float* __restrict__ u,
                    const float* __restrict__ A1, const float* __restrict__ c1,
                    const float* __restrict__ A2, const float* __restrict__ c2,
                    const float* __restrict__ A3, const float* __restrict__ c3,
                    const float* __restrict__ A4, const float* __restrict__ c4,
                    const float* __restrict__ A5, const float* __restrict__ c5,
                    float* __restrict__ out, int G) {
    int wid = (blockIdx.x * blockDim.x + threadIdx.x) >> 6;  // wave = graph
    int lane = threadIdx.x & 63;
    if (wid >= G) return;
    int g = wid;

    float zreg = pooled[g * H + lane];
    float u0 = u[g * 4 + 0], u1 = u[g * 4 + 1], u2 = u[g * 4 + 2], u3 = u[g * 4 + 3];

    // layer 1: 68 -> 50
    float acc = (lane < 50) ? c1[lane] : 0.f;
#pragma unroll
    for (int k = 0; k < 64; ++k) {
        float zk = __shfl(zreg, k);
        float w = (lane < 50) ? A1[k * 50 + lane] : 0.f;
        acc = fmaf(zk, w, acc);
    }
    {
        float w;
        w = (lane < 50) ? A1[64 * 50 + lane] : 0.f; acc = fmaf(u0, w, acc);
        w = (lane < 50) ? A1[65 * 50 + lane] : 0.f; acc = fmaf(u1, w, acc);
        w = (lane < 50) ? A1[66 * 50 + lane] : 0.f; acc = fmaf(u2, w, acc);
        w = (lane < 50) ? A1[67 * 50 + lane] : 0.f; acc = fmaf(u3, w, acc);
    }
    float z1v = fmaxf(acc, 0.f);

    // layer 2: 50 -> 30
    acc = (lane < 30) ? c2[lane] : 0.f;
#pragma unroll
    for (int k = 0; k < 50; ++k) {
        float zk = __shfl(z1v, k);
        float w = (lane < 30) ? A2[k * 30 + lane] : 0.f;
        acc = fmaf(zk, w, acc);
    }
    float z2v = fmaxf(acc, 0.f);

    // layer 3: 30 -> 20
    acc = (lane < 20) ? c3[lane] : 0.f;
#pragma unroll
    for (int k = 0; k < 30; ++k) {
        float zk = __shfl(z2v, k);
        float w = (lane < 20) ? A3[k * 20 + lane] : 0.f;
        acc = fmaf(zk, w, acc);
    }
    float z3v = fmaxf(acc, 0.f);

    // layer 4: 20 -> 5
    acc = (lane < 5) ? c4[lane] : 0.f;
#pragma unroll
    for (int k = 0; k < 20; ++k) {
        float zk = __shfl(z3v, k);
        float w = (lane < 5) ? A4[k * 5 + lane] : 0.f;
        acc = fmaf(zk, w, acc);
    }
    float z4v = fmaxf(acc, 0.f);

    // layer 5: 5 -> 1
    acc = c5[0];
#pragma unroll
    for (int k = 0; k < 5; ++k) {
        float zk = __shfl(z4v, k);
        acc = fmaf(zk, A5[k], acc);
    }
    if (lane == 0) out[g] = fmaxf(acc, 0.f);
}

extern "C" void kernel_launch(void* const* d_in, const int* in_sizes, int n_in,
                              void* d_out, int out_size, void* d_ws, size_t ws_size,
                              hipStream_t stream) {
    const float* x     = (const float*)d_in[0];
    const int*   edge  = (const int*)d_in[1];
    const int*   batch = (const int*)d_in[2];
    const float* u     = (const float*)d_in[3];
    const float* W1 = (const float*)d_in[4];  const float* b1 = (const float*)d_in[5];
    const float* W2 = (const float*)d_in[6];  const float* b2 = (const float*)d_in[7];
    const float* W3 = (const float*)d_in[8];  const float* b3 = (const float*)d_in[9];
    const float* A1 = (const float*)d_in[10]; const float* c1 = (const float*)d_in[11];
    const float* A2 = (const float*)d_in[12]; const float* c2 = (const float*)d_in[13];
    const float* A3 = (const float*)d_in[14]; const float* c3 = (const float*)d_in[15];
    const float* A4 = (const float*)d_in[16]; const float* c4 = (const float*)d_in[17];
    const float* A5 = (const float*)d_in[18]; const float* c5 = (const float*)d_in[19];

    const int N = in_sizes[2];          // 100000
    const int E = in_sizes[1] / 2;      // 3200000
    const int G = in_sizes[3] / 4;      // 256
    const int* src = edge;
    const int* dst = edge + E;
    const int nbuck = (N + BNODES - 1) >> BNODE_SHIFT;   // 391

    // ---- workspace layout (pairs4 aliases hb region: pairs4 dead before lin_h writes) ----
    char* ws = (char*)d_ws;
    size_t off = 0;
    auto alloc = [&](size_t bytes) -> void* {
        void* p = ws + off;
        off = (off + bytes + 255) & ~(size_t)255;
        return p;
    };
    ushort* hb       = (ushort*)alloc((size_t)N * H * 2);  // bf16 gather operand; aliases pairs4 (E*4 <= N*H*2)
    float*  h        = (float*)alloc((size_t)N * H * 4);
    int*    col      = (int*)alloc((size_t)E * 4);
    ushort* xb       = (ushort*)alloc((size_t)N * 16 * 2);
    int*    rowstart = (int*)alloc((size_t)(N + 1) * 4);
    float*  dinv     = (float*)alloc((size_t)N * 4);
    int*    bcounts  = (int*)alloc((size_t)nbuck * 4);
    int*    boff     = (int*)alloc((size_t)(nbuck + 1) * 4);
    int*    bcur     = (int*)alloc((size_t)nbuck * 64);    // 64B-padded cursors
    int*    nodestart= (int*)alloc((size_t)(G + 1) * 4);
    float*  pooled   = (float*)alloc((size_t)G * H * 4);
    int*    pairs4   = (int*)hb;

    const int nbN   = (N + 255) / 256;
    const int nbAgg = (N + 3) / 4;       // 4 waves/block, wave per node
    const int nchunks = (E + CHUNK - 1) / CHUNK;

    // ---- CSR build via block-local LDS sort ----
    zero_i32<<<(nbuck + 255) / 256, 256, 0, stream>>>(bcounts, nbuck);
    bucket_hist<<<256, 256, 0, stream>>>(dst, E, bcounts, nbuck);
    bucket_scan<<<1, 1024, 0, stream>>>(bcounts, boff, bcur, rowstart, nbuck, E, N);
    edge_sort_scatter<<<nchunks, 256, 0, stream>>>(src, dst, E, nbuck, bcur, pairs4);
    bucket_build<<<nbuck, 256, 0, stream>>>(pairs4, boff, col, rowstart, dinv, N);
    graph_bounds<<<nbN, 256, 0, stream>>>(batch, nodestart, N, G);

    // ---- conv1 (fused: aggregate 9-wide raw bf16 x, then W1) ----
    prep_xb<<<(N * 16 + 255) / 256, 256, 0, stream>>>(x, dinv, xb, N);
    conv1_fused<<<nbAgg, 256, 0, stream>>>(xb, dinv, rowstart, rowstart + 1, col, W1, b1, h, N);
    // ---- conv2 ----
    lin_h<<<(N + 15) / 16, 256, 0, stream>>>(h, W2, dinv, hb, N);
    aggregate_b<<<nbAgg, 256, 0, stream>>>(hb, dinv, rowstart, rowstart + 1, col, b2, h, N);
    // ---- conv3 ----
    lin_h<<<(N + 15) / 16, 256, 0, stream>>>(h, W3, dinv, hb, N);
    aggregate_b<<<nbAgg, 256, 0, stream>>>(hb, dinv, rowstart, rowstart + 1, col, b3, h, N);

    // ---- mean pool + final MLP ----
    pool_mean<<<G, 256, 0, stream>>>(h, nodestart, pooled, G);
    mlp<<<(G * 64 + 255) / 256, 256, 0, stream>>>(pooled, u, A1, c1, A2, c2, A3, c3,
                                                  A4, c4, A5, c5, (float*)d_out, G);
}

// Round 8
// 417.195 us; speedup vs baseline: 4.0215x; 1.0230x over previous
//
#include <hip/hip_runtime.h>

#define H 64
#define BNODE_SHIFT 8           // 256 nodes per bucket
#define BNODES 256
#define CHUNK 3072              // edges per sort block (12 per thread)
#define EPT 12

// bf16 helpers: bf16->fp32 is exact (bit shift); fp32->bf16 round-to-nearest-even
static __device__ __forceinline__ float b2f(ushort b) {
    return __uint_as_float(((unsigned int)b) << 16);
}
static __device__ __forceinline__ ushort f2b(float f) {
    unsigned int u = __float_as_uint(f);
    return (ushort)((u + 0x7FFF + ((u >> 16) & 1)) >> 16);
}

// ---------------- zero-fill ----------------
__global__ void zero_i32(int* p, int n) {
    int i = blockIdx.x * blockDim.x + threadIdx.x;
    if (i < n) p[i] = 0;
}

// ---------------- bucket histogram (LDS-local then merge) ----------------
__global__ void bucket_hist(const int* __restrict__ dst, int E,
                            int* __restrict__ bcounts, int nbuck) {
    __shared__ int hist[512];
    for (int i = threadIdx.x; i < nbuck; i += blockDim.x) hist[i] = 0;
    __syncthreads();
    for (int e = blockIdx.x * blockDim.x + threadIdx.x; e < E; e += gridDim.x * blockDim.x)
        atomicAdd(&hist[dst[e] >> BNODE_SHIFT], 1);
    __syncthreads();
    for (int i = threadIdx.x; i < nbuck; i += blockDim.x) {
        int v = hist[i];
        if (v) atomicAdd(&bcounts[i], v);
    }
}

// ---------------- bucket offsets scan (1 block) ----------------
__global__ void bucket_scan(const int* __restrict__ bcounts, int* __restrict__ boff,
                            int* __restrict__ bcur, int* __restrict__ rowstart,
                            int nbuck, int E, int N) {
    __shared__ int t[1024];
    int tid = threadIdx.x;
    int v = (tid < nbuck) ? bcounts[tid] : 0;
    t[tid] = v;
    __syncthreads();
    for (int off = 1; off < 1024; off <<= 1) {
        int x = (tid >= off) ? t[tid - off] : 0;
        __syncthreads();
        t[tid] += x;
        __syncthreads();
    }
    if (tid < nbuck) {
        int o = t[tid] - v;       // exclusive
        boff[tid] = o;
        bcur[tid * 16] = o;       // 64B-padded cursor
    }
    if (tid == 0) { boff[nbuck] = E; rowstart[N] = E; }
}

// ---------------- block-local LDS sort + coalesced flush ----------------
// pack: src (bits 0..19) | local_dst (bits 20..27)
__global__ void edge_sort_scatter(const int* __restrict__ src, const int* __restrict__ dst,
                                  int E, int nbuck,
                                  int* __restrict__ bcur, int* __restrict__ pairs4) {
    __shared__ int hist[392];
    __shared__ int bstart[393];
    __shared__ int cur[392];
    __shared__ int gbase[392];
    __shared__ int wsum[256];
    __shared__ int packed[CHUNK];   // 12 KB

    int t = threadIdx.x;
    int chunkBase = blockIdx.x * CHUNK;

    // phase 1: local histogram
    for (int i = t; i < nbuck; i += 256) hist[i] = 0;
    __syncthreads();
#pragma unroll
    for (int k = 0; k < EPT; ++k) {
        int e = chunkBase + t + k * 256;
        if (e < E) atomicAdd(&hist[dst[e] >> BNODE_SHIFT], 1);
    }
    __syncthreads();

    // phase 2: exclusive scan of hist
    int a0 = (2 * t < nbuck) ? hist[2 * t] : 0;
    int a1 = (2 * t + 1 < nbuck) ? hist[2 * t + 1] : 0;
    int s2 = a0 + a1;
    wsum[t] = s2;
    __syncthreads();
    for (int off = 1; off < 256; off <<= 1) {
        int x = (t >= off) ? wsum[t - off] : 0;
        __syncthreads();
        wsum[t] += x;
        __syncthreads();
    }
    int base = wsum[t] - s2;        // exclusive
    if (2 * t < nbuck)     bstart[2 * t] = base;
    if (2 * t + 1 < nbuck) bstart[2 * t + 1] = base + a0;
    if (t == 255) bstart[nbuck] = wsum[255];
    __syncthreads();

    // phase 2b: reserve global spans; init local cursors
    for (int b = t; b < nbuck; b += 256) {
        int cnt = bstart[b + 1] - bstart[b];
        gbase[b] = cnt ? atomicAdd(&bcur[b * 16], cnt) : 0;
        cur[b] = bstart[b];
    }
    __syncthreads();

    // phase 3: place edges sorted into LDS
#pragma unroll
    for (int k = 0; k < EPT; ++k) {
        int e = chunkBase + t + k * 256;
        if (e < E) {
            int d = dst[e];
            int b = d >> BNODE_SHIFT;
            int pos = atomicAdd(&cur[b], 1);
            packed[pos] = src[e] | ((d & (BNODES - 1)) << 20);
        }
    }
    __syncthreads();

    // phase 4: coalesced flush, one bucket run per wave
    int w = t >> 6, lane = t & 63;
    for (int b = w; b < nbuck; b += 4) {
        int lb = bstart[b], le = bstart[b + 1];
        int gb = gbase[b];
        for (int j = lb + lane; j < le; j += 64)
            pairs4[gb + (j - lb)] = packed[j];
    }
}

// ---------------- exact CSR within each bucket (LDS atomics) ----------------
__global__ void bucket_build(const int* __restrict__ pairs4, const int* __restrict__ boff,
                             int* __restrict__ col, int* __restrict__ rowstart,
                             float* __restrict__ dinv, int N) {
    __shared__ int hist[BNODES];
    __shared__ int cur[BNODES];
    int b = blockIdx.x;
    int lo = boff[b], hi = boff[b + 1];
    int node0 = b << BNODE_SHIFT;
    int tid = threadIdx.x;
    hist[tid] = 0;
    __syncthreads();
    for (int e = lo + tid; e < hi; e += 256)
        atomicAdd(&hist[(pairs4[e] >> 20) & (BNODES - 1)], 1);
    __syncthreads();
    int v = hist[tid];
    cur[tid] = v;
    __syncthreads();
    for (int off = 1; off < BNODES; off <<= 1) {
        int x = (tid >= off) ? cur[tid - off] : 0;
        __syncthreads();
        cur[tid] += x;
        __syncthreads();
    }
    {
        int ex = cur[tid] - v;    // exclusive
        int node = node0 + tid;
        if (node < N) {
            rowstart[node] = lo + ex;
            dinv[node] = rsqrtf((float)(v + 1));   // +1 self-loop
        }
        cur[tid] = ex;            // local cursor
    }
    __syncthreads();
    for (int e = lo + tid; e < hi; e += 256) {
        int pr = pairs4[e];
        int p = atomicAdd(&cur[(pr >> 20) & (BNODES - 1)], 1);
        col[lo + p] = pr & 0xFFFFF;
    }
}

// ---------------- graph boundaries from sorted batch (no atomics) ----------------
__global__ void graph_bounds(const int* __restrict__ batch, int* __restrict__ nodestart,
                             int N, int G) {
    int i = blockIdx.x * blockDim.x + threadIdx.x;
    if (i >= N) return;
    int b = batch[i];
    int bp = (i == 0) ? -1 : batch[i - 1];
    for (int g = bp + 1; g <= b; ++g) nodestart[g] = i;
    if (i == N - 1) nodestart[G] = N;
}

// ---------------- segmented mean pool: one block per graph ----------------
__global__ void pool_mean(const float* __restrict__ h, const int* __restrict__ nodestart,
                          float* __restrict__ pooled, int G) {
    int g = blockIdx.x;
    int lo = nodestart[g], hi = nodestart[g + 1];
    int f = threadIdx.x & 63, w = threadIdx.x >> 6;
    float acc = 0.f;
    for (int n = lo + w; n < hi; n += 4) acc += h[(size_t)n * H + f];
    __shared__ float red[4][64];
    red[w][f] = acc;
    __syncthreads();
    if (w == 0) {
        float s = red[0][f] + red[1][f] + red[2][f] + red[3][f];
        float c = (float)(hi - lo);
        pooled[g * H + f] = s / fmaxf(c, 1.f);
    }
}

// ---------------- prep: pad x to 16 bf16/row (32B), pre-scaled by dinv ----------------
__global__ void prep_xb(const float* __restrict__ x, const float* __restrict__ dinv,
                        ushort* __restrict__ xb, int N) {
    int i = blockIdx.x * blockDim.x + threadIdx.x;
    if (i >= N * 16) return;
    int n = i >> 4, k = i & 15;
    xb[i] = (k < 9) ? f2b(x[n * 9 + k] * dinv[n]) : (ushort)0;
}

// ---------------- conv1 fused: agg = dinv_i*(sum xb[src] + xb[i]); out = relu(agg@W1+b1)
__global__ void conv1_fused(const ushort* __restrict__ xb, const float* __restrict__ dinv,
                            const int* __restrict__ rowstart,
                            const int* __restrict__ col, const float* __restrict__ W1,
                            const float* __restrict__ b1, float* __restrict__ out, int N) {
    int gtid = blockIdx.x * blockDim.x + threadIdx.x;
    int i = __builtin_amdgcn_readfirstlane(gtid >> 6);
    int lane = threadIdx.x & 63;
    int f16 = lane & 15, grp = lane >> 4;
    if (i >= N) return;
    float di = dinv[i];
    float sv = b2f(xb[(size_t)i * 16 + f16]);   // self (already dinv_i-scaled)
    float acc = 0.f;
    int s = rowstart[i], e = rowstart[i + 1];
    for (int base = s; base < e; base += 64) {
        int cnt = e - base;
        if (cnt > 64) cnt = 64;
        int idx = 0;
        if (lane < cnt) idx = col[base + lane];
        for (int j = 0; j < cnt; j += 8) {
            int j0 = j + grp, j1 = j + 4 + grp;
            int s0 = __shfl(idx, j0);
            int s1 = __shfl(idx, j1 & 63);
            float v0 = (j0 < cnt) ? b2f(xb[(size_t)s0 * 16 + f16]) : 0.f;
            float v1 = (j1 < cnt) ? b2f(xb[(size_t)s1 * 16 + f16]) : 0.f;
            acc += v0 + v1;
        }
    }
    // reduce 4 edge-groups
    acc += __shfl_xor(acc, 16);
    acc += __shfl_xor(acc, 32);
    float aggf = di * (acc + sv);            // lane k (k<9) holds agg[k]

    float o = b1[lane];
#pragma unroll
    for (int k = 0; k < 9; ++k) {
        float ak = __shfl(aggf, k);
        o = fmaf(ak, W1[k * H + lane], o);
    }
    out[(size_t)i * H + lane] = fmaxf(o, 0.f);
}

// ---------------- linear: N x 64 @ 64 x 64 (16 nodes/block), scaled, bf16 out ----------------
__global__ void lin_h(const float* __restrict__ h, const float* __restrict__ W,
                      const float* __restrict__ dinv, ushort* __restrict__ out, int N) {
    __shared__ float Ws[H * H];     // 16 KB
    __shared__ float hs[16 * H];    // 4 KB
    int tid = threadIdx.x;
    int node0 = blockIdx.x * 16;
    for (int idx = tid; idx < H * H; idx += 256) Ws[idx] = W[idx];
    for (int idx = tid; idx < 16 * H; idx += 256) {
        int n = node0 + (idx >> 6);
        hs[idx] = (n < N) ? h[n * H + (idx & 63)] : 0.f;
    }
    __syncthreads();
    int nlb = tid >> 6, f = tid & 63;
    float a0 = 0.f, a1 = 0.f, a2 = 0.f, a3 = 0.f;
#pragma unroll 8
    for (int k = 0; k < H; ++k) {
        float w = Ws[k * H + f];
        a0 += hs[(nlb) * H + k] * w;
        a1 += hs[(nlb + 4) * H + k] * w;
        a2 += hs[(nlb + 8) * H + k] * w;
        a3 += hs[(nlb + 12) * H + k] * w;
    }
    int n;
    n = node0 + nlb;      if (n < N) out[n * H + f] = f2b(a0 * dinv[n]);
    n = node0 + nlb + 4;  if (n < N) out[n * H + f] = f2b(a1 * dinv[n]);
    n = node0 + nlb + 8;  if (n < N) out[n * H + f] = f2b(a2 * dinv[n]);
    n = node0 + nlb + 12; if (n < N) out[n * H + f] = f2b(a3 * dinv[n]);
}

// ---------------- aggregate (bf16 gather, scalarized indices) ----------------
// wave per node; i/bounds/indices wave-uniform -> SGPRs; lane = feature.
// hb pre-scaled by dinv[src]; out = relu(bias + dinv_i*(sum hb[src] + hb[i]))
__global__ void aggregate_b(const ushort* __restrict__ hb, const float* __restrict__ dinv,
                            const int* __restrict__ rowstart,
                            const int* __restrict__ col, const float* __restrict__ bias,
                            float* __restrict__ out, int N) {
    int gtid = blockIdx.x * blockDim.x + threadIdx.x;
    int i = __builtin_amdgcn_readfirstlane(gtid >> 6);   // node = wave (uniform, SGPR)
    int f = threadIdx.x & 63;
    if (i >= N) return;
    float acc = b2f(hb[(size_t)i * H + f]);  // self-loop term (dinv_i*hw[i])
    int s = rowstart[i], e = rowstart[i + 1];
    int p = s;
    for (; p + 8 <= e; p += 8) {
        int i0 = __builtin_amdgcn_readfirstlane(col[p + 0]);
        int i1 = __builtin_amdgcn_readfirstlane(col[p + 1]);
        int i2 = __builtin_amdgcn_readfirstlane(col[p + 2]);
        int i3 = __builtin_amdgcn_readfirstlane(col[p + 3]);
        int i4 = __builtin_amdgcn_readfirstlane(col[p + 4]);
        int i5 = __builtin_amdgcn_readfirstlane(col[p + 5]);
        int i6 = __builtin_amdgcn_readfirstlane(col[p + 6]);
        int i7 = __builtin_amdgcn_readfirstlane(col[p + 7]);
        float v0 = b2f(hb[(size_t)i0 * H + f]);
        float v1 = b2f(hb[(size_t)i1 * H + f]);
        float v2 = b2f(hb[(size_t)i2 * H + f]);
        float v3 = b2f(hb[(size_t)i3 * H + f]);
        float v4 = b2f(hb[(size_t)i4 * H + f]);
        float v5 = b2f(hb[(size_t)i5 * H + f]);
        float v6 = b2f(hb[(size_t)i6 * H + f]);
        float v7 = b2f(hb[(size_t)i7 * H + f]);
        acc += ((v0 + v1) + (v2 + v3)) + ((v4 + v5) + (v6 + v7));
    }
    for (; p < e; ++p) {
        int s0 = __builtin_amdgcn_readfirstlane(col[p]);
        acc += b2f(hb[(size_t)s0 * H + f]);
    }
    out[(size_t)i * H + f] = fmaxf(bias[f] + dinv[i] * acc, 0.f);
}

// ---------------- final MLP: one wave per graph, shfl-based ----------------
__global__ void mlp(const float* __restrict__ pooled, const float* __restrict__ u,
                    const float* __restrict__ A1, const float* __restrict__ c1,
                    const float* __restrict__ A2, const float* __restrict__ c2,
                    const float* __restrict__ A3, const float* __restrict__ c3,
                    const float* __restrict__ A4, const float* __restrict__ c4,
                    const float* __restrict__ A5, const float* __restrict__ c5,
                    float* __restrict__ out, int G) {
    int wid = (blockIdx.x * blockDim.x + threadIdx.x) >> 6;  // wave = graph
    int lane = threadIdx.x & 63;
    if (wid >= G) return;
    int g = wid;

    float zreg = pooled[g * H + lane];
    float u0 = u[g * 4 + 0], u1 = u[g * 4 + 1], u2 = u[g * 4 + 2], u3 = u[g * 4 + 3];

    // layer 1: 68 -> 50
    float acc = (lane < 50) ? c1[lane] : 0.f;
#pragma unroll
    for (int k = 0; k < 64; ++k) {
        float zk = __shfl(zreg, k);
        float w = (lane < 50) ? A1[k * 50 + lane] : 0.f;
        acc = fmaf(zk, w, acc);
    }
    {
        float w;
        w = (lane < 50) ? A1[64 * 50 + lane] : 0.f; acc = fmaf(u0, w, acc);
        w = (lane < 50) ? A1[65 * 50 + lane] : 0.f; acc = fmaf(u1, w, acc);
        w = (lane < 50) ? A1[66 * 50 + lane] : 0.f; acc = fmaf(u2, w, acc);
        w = (lane < 50) ? A1[67 * 50 + lane] : 0.f; acc = fmaf(u3, w, acc);
    }
    float z1v = fmaxf(acc, 0.f);

    // layer 2: 50 -> 30
    acc = (lane < 30) ? c2[lane] : 0.f;
#pragma unroll
    for (int k = 0; k < 50; ++k) {
        float zk = __shfl(z1v, k);
        float w = (lane < 30) ? A2[k * 30 + lane] : 0.f;
        acc = fmaf(zk, w, acc);
    }
    float z2v = fmaxf(acc, 0.f);

    // layer 3: 30 -> 20
    acc = (lane < 20) ? c3[lane] : 0.f;
#pragma unroll
    for (int k = 0; k < 30; ++k) {
        float zk = __shfl(z2v, k);
        float w = (lane < 20) ? A3[k * 20 + lane] : 0.f;
        acc = fmaf(zk, w, acc);
    }
    float z3v = fmaxf(acc, 0.f);

    // layer 4: 20 -> 5
    acc = (lane < 5) ? c4[lane] : 0.f;
#pragma unroll
    for (int k = 0; k < 20; ++k) {
        float zk = __shfl(z3v, k);
        float w = (lane < 5) ? A4[k * 5 + lane] : 0.f;
        acc = fmaf(zk, w, acc);
    }
    float z4v = fmaxf(acc, 0.f);

    // layer 5: 5 -> 1
    acc = c5[0];
#pragma unroll
    for (int k = 0; k < 5; ++k) {
        float zk = __shfl(z4v, k);
        acc = fmaf(zk, A5[k], acc);
    }
    if (lane == 0) out[g] = fmaxf(acc, 0.f);
}

extern "C" void kernel_launch(void* const* d_in, const int* in_sizes, int n_in,
                              void* d_out, int out_size, void* d_ws, size_t ws_size,
                              hipStream_t stream) {
    const float* x     = (const float*)d_in[0];
    const int*   edge  = (const int*)d_in[1];
    const int*   batch = (const int*)d_in[2];
    const float* u     = (const float*)d_in[3];
    const float* W1 = (const float*)d_in[4];  const float* b1 = (const float*)d_in[5];
    const float* W2 = (const float*)d_in[6];  const float* b2 = (const float*)d_in[7];
    const float* W3 = (const float*)d_in[8];  const float* b3 = (const float*)d_in[9];
    const float* A1 = (const float*)d_in[10]; const float* c1 = (const float*)d_in[11];
    const float* A2 = (const float*)d_in[12]; const float* c2 = (const float*)d_in[13];
    const float* A3 = (const float*)d_in[14]; const float* c3 = (const float*)d_in[15];
    const float* A4 = (const float*)d_in[16]; const float* c4 = (const float*)d_in[17];
    const float* A5 = (const float*)d_in[18]; const float* c5 = (const float*)d_in[19];

    const int N = in_sizes[2];          // 100000
    const int E = in_sizes[1] / 2;      // 3200000
    const int G = in_sizes[3] / 4;      // 256
    const int* src = edge;
    const int* dst = edge + E;
    const int nbuck = (N + BNODES - 1) >> BNODE_SHIFT;   // 391

    // ---- workspace layout (pairs4 aliases hb region: pairs4 dead before lin_h writes) ----
    char* ws = (char*)d_ws;
    size_t off = 0;
    auto alloc = [&](size_t bytes) -> void* {
        void* p = ws + off;
        off = (off + bytes + 255) & ~(size_t)255;
        return p;
    };
    ushort* hb       = (ushort*)alloc((size_t)N * H * 2);  // bf16 gather operand; aliases pairs4
    float*  h        = (float*)alloc((size_t)N * H * 4);
    int*    col      = (int*)alloc((size_t)E * 4);
    ushort* xb       = (ushort*)alloc((size_t)N * 16 * 2);
    int*    rowstart = (int*)alloc((size_t)(N + 1) * 4);
    float*  dinv     = (float*)alloc((size_t)N * 4);
    int*    bcounts  = (int*)alloc((size_t)nbuck * 4);
    int*    boff     = (int*)alloc((size_t)(nbuck + 1) * 4);
    int*    bcur     = (int*)alloc((size_t)nbuck * 64);    // 64B-padded cursors
    int*    nodestart= (int*)alloc((size_t)(G + 1) * 4);
    float*  pooled   = (float*)alloc((size_t)G * H * 4);
    int*    pairs4   = (int*)hb;

    const int nbN   = (N + 255) / 256;
    const int nbAgg = (N + 3) / 4;       // 4 waves/block, wave per node
    const int nchunks = (E + CHUNK - 1) / CHUNK;   // 1042

    // ---- CSR build via block-local LDS sort ----
    zero_i32<<<(nbuck + 255) / 256, 256, 0, stream>>>(bcounts, nbuck);
    bucket_hist<<<256, 256, 0, stream>>>(dst, E, bcounts, nbuck);
    bucket_scan<<<1, 1024, 0, stream>>>(bcounts, boff, bcur, rowstart, nbuck, E, N);
    edge_sort_scatter<<<nchunks, 256, 0, stream>>>(src, dst, E, nbuck, bcur, pairs4);
    bucket_build<<<nbuck, 256, 0, stream>>>(pairs4, boff, col, rowstart, dinv, N);
    graph_bounds<<<nbN, 256, 0, stream>>>(batch, nodestart, N, G);

    // ---- conv1 (fused: aggregate 9-wide raw bf16 x, then W1) ----
    prep_xb<<<(N * 16 + 255) / 256, 256, 0, stream>>>(x, dinv, xb, N);
    conv1_fused<<<nbAgg, 256, 0, stream>>>(xb, dinv, rowstart, col, W1, b1, h, N);
    // ---- conv2 ----
    lin_h<<<(N + 15) / 16, 256, 0, stream>>>(h, W2, dinv, hb, N);
    aggregate_b<<<nbAgg, 256, 0, stream>>>(hb, dinv, rowstart, col, b2, h, N);
    // ---- conv3 ----
    lin_h<<<(N + 15) / 16, 256, 0, stream>>>(h, W3, dinv, hb, N);
    aggregate_b<<<nbAgg, 256, 0, stream>>>(hb, dinv, rowstart, col, b3, h, N);

    // ---- mean pool + final MLP ----
    pool_mean<<<G, 256, 0, stream>>>(h, nodestart, pooled, G);
    mlp<<<(G * 64 + 255) / 256, 256, 0, stream>>>(pooled, u, A1, c1, A2, c2, A3, c3,
                                                  A4, c4, A5, c5, (float*)d_out, G);
}

// Round 9
// 390.472 us; speedup vs baseline: 4.2967x; 1.0684x over previous
//
#include <hip/hip_runtime.h>

#define H 64
#define BNODE_SHIFT 8           // 256 nodes per bucket
#define BNODES 256
#define CHUNK 4096              // edges per sort block (16 per thread)
#define EPT 16

// bf16 helpers: bf16->fp32 is exact (bit shift); fp32->bf16 round-to-nearest-even
static __device__ __forceinline__ float b2f(ushort b) {
    return __uint_as_float(((unsigned int)b) << 16);
}
static __device__ __forceinline__ ushort f2b(float f) {
    unsigned int u = __float_as_uint(f);
    return (ushort)((u + 0x7FFF + ((u >> 16) & 1)) >> 16);
}

// ---------------- zero-fill ----------------
__global__ void zero_i32(int* p, int n) {
    int i = blockIdx.x * blockDim.x + threadIdx.x;
    if (i < n) p[i] = 0;
}

// ---------------- bucket histogram (LDS-local then merge) ----------------
__global__ void bucket_hist(const int* __restrict__ dst, int E,
                            int* __restrict__ bcounts, int nbuck) {
    __shared__ int hist[512];
    for (int i = threadIdx.x; i < nbuck; i += blockDim.x) hist[i] = 0;
    __syncthreads();
    for (int e = blockIdx.x * blockDim.x + threadIdx.x; e < E; e += gridDim.x * blockDim.x)
        atomicAdd(&hist[dst[e] >> BNODE_SHIFT], 1);
    __syncthreads();
    for (int i = threadIdx.x; i < nbuck; i += blockDim.x) {
        int v = hist[i];
        if (v) atomicAdd(&bcounts[i], v);
    }
}

// ---------------- bucket offsets scan (1 block) ----------------
__global__ void bucket_scan(const int* __restrict__ bcounts, int* __restrict__ boff,
                            int* __restrict__ bcur, int* __restrict__ rowstart,
                            int nbuck, int E, int N) {
    __shared__ int t[1024];
    int tid = threadIdx.x;
    int v = (tid < nbuck) ? bcounts[tid] : 0;
    t[tid] = v;
    __syncthreads();
    for (int off = 1; off < 1024; off <<= 1) {
        int x = (tid >= off) ? t[tid - off] : 0;
        __syncthreads();
        t[tid] += x;
        __syncthreads();
    }
    if (tid < nbuck) {
        int o = t[tid] - v;       // exclusive
        boff[tid] = o;
        bcur[tid * 16] = o;       // 64B-padded cursor
    }
    if (tid == 0) { boff[nbuck] = E; rowstart[N] = E; }
}

// ---------------- block-local LDS sort + fully parallel flush ----------------
// pack: src (bits 0..19) | local_dst (bits 20..27)
__global__ void edge_sort_scatter(const int* __restrict__ src, const int* __restrict__ dst,
                                  int E, int nbuck,
                                  int* __restrict__ bcur, int* __restrict__ pairs4) {
    __shared__ int hist[392];
    __shared__ int bstart[393];
    __shared__ int cur[392];
    __shared__ int gbase[392];
    __shared__ int wsum[256];
    __shared__ int packed[CHUNK];   // 16 KB
    __shared__ int gpos[CHUNK];     // 16 KB

    int t = threadIdx.x;
    int chunkBase = blockIdx.x * CHUNK;

    // phase 1: local histogram
    for (int i = t; i < nbuck; i += 256) hist[i] = 0;
    __syncthreads();
#pragma unroll
    for (int k = 0; k < EPT; ++k) {
        int e = chunkBase + t + k * 256;
        if (e < E) atomicAdd(&hist[dst[e] >> BNODE_SHIFT], 1);
    }
    __syncthreads();

    // phase 2: exclusive scan of hist (2 items/thread covers <=512 buckets)
    int a0 = (2 * t < nbuck) ? hist[2 * t] : 0;
    int a1 = (2 * t + 1 < nbuck) ? hist[2 * t + 1] : 0;
    int s2 = a0 + a1;
    wsum[t] = s2;
    __syncthreads();
    for (int off = 1; off < 256; off <<= 1) {
        int x = (t >= off) ? wsum[t - off] : 0;
        __syncthreads();
        wsum[t] += x;
        __syncthreads();
    }
    int base = wsum[t] - s2;        // exclusive
    if (2 * t < nbuck)     bstart[2 * t] = base;
    if (2 * t + 1 < nbuck) bstart[2 * t + 1] = base + a0;
    if (t == 255) bstart[nbuck] = wsum[255];
    __syncthreads();

    // phase 2b: reserve global spans; init local cursors
    for (int b = t; b < nbuck; b += 256) {
        int cnt = bstart[b + 1] - bstart[b];
        gbase[b] = cnt ? (atomicAdd(&bcur[b * 16], cnt) - bstart[b]) : 0;
        cur[b] = bstart[b];
    }
    __syncthreads();

    // phase 3: place edges sorted into LDS; record final global position
    #pragma unroll
    for (int k = 0; k < EPT; ++k) {
        int e = chunkBase + t + k * 256;
        if (e < E) {
            int d = dst[e];
            int b = d >> BNODE_SHIFT;
            int pos = atomicAdd(&cur[b], 1);
            packed[pos] = src[e] | ((d & (BNODES - 1)) << 20);
            gpos[pos] = gbase[b] + pos;   // gbase pre-biased by -bstart[b]
        }
    }
    __syncthreads();

    // phase 4: flat parallel flush (coalesced LDS read; runs are contiguous globally)
    int nloc = bstart[nbuck];
    for (int j = t; j < nloc; j += 256)
        pairs4[gpos[j]] = packed[j];
}

// ---------------- exact CSR within each bucket (LDS atomics) ----------------
__global__ void bucket_build(const int* __restrict__ pairs4, const int* __restrict__ boff,
                             int* __restrict__ col, int* __restrict__ rowstart,
                             float* __restrict__ dinv, int N) {
    __shared__ int hist[BNODES];
    __shared__ int cur[BNODES];
    int b = blockIdx.x;
    int lo = boff[b], hi = boff[b + 1];
    int node0 = b << BNODE_SHIFT;
    int tid = threadIdx.x;
    hist[tid] = 0;
    __syncthreads();
    for (int e = lo + tid; e < hi; e += 256)
        atomicAdd(&hist[(pairs4[e] >> 20) & (BNODES - 1)], 1);
    __syncthreads();
    int v = hist[tid];
    cur[tid] = v;
    __syncthreads();
    for (int off = 1; off < BNODES; off <<= 1) {
        int x = (tid >= off) ? cur[tid - off] : 0;
        __syncthreads();
        cur[tid] += x;
        __syncthreads();
    }
    {
        int ex = cur[tid] - v;    // exclusive
        int node = node0 + tid;
        if (node < N) {
            rowstart[node] = lo + ex;
            dinv[node] = rsqrtf((float)(v + 1));   // +1 self-loop
        }
        cur[tid] = ex;            // local cursor
    }
    __syncthreads();
    for (int e = lo + tid; e < hi; e += 256) {
        int pr = pairs4[e];
        int p = atomicAdd(&cur[(pr >> 20) & (BNODES - 1)], 1);
        col[lo + p] = pr & 0xFFFFF;
    }
}

// ---------------- graph boundaries from sorted batch (no atomics) ----------------
__global__ void graph_bounds(const int* __restrict__ batch, int* __restrict__ nodestart,
                             int N, int G) {
    int i = blockIdx.x * blockDim.x + threadIdx.x;
    if (i >= N) return;
    int b = batch[i];
    int bp = (i == 0) ? -1 : batch[i - 1];
    for (int g = bp + 1; g <= b; ++g) nodestart[g] = i;
    if (i == N - 1) nodestart[G] = N;
}

// ---------------- segmented mean pool: one block per graph ----------------
__global__ void pool_mean(const float* __restrict__ h, const int* __restrict__ nodestart,
                          float* __restrict__ pooled, int G) {
    int g = blockIdx.x;
    int lo = nodestart[g], hi = nodestart[g + 1];
    int f = threadIdx.x & 63, w = threadIdx.x >> 6;
    float acc = 0.f;
    for (int n = lo + w; n < hi; n += 4) acc += h[(size_t)n * H + f];
    __shared__ float red[4][64];
    red[w][f] = acc;
    __syncthreads();
    if (w == 0) {
        float s = red[0][f] + red[1][f] + red[2][f] + red[3][f];
        float c = (float)(hi - lo);
        pooled[g * H + f] = s / fmaxf(c, 1.f);
    }
}

// ---------------- prep: pad x to 16 bf16/row (32B), pre-scaled by dinv ----------------
__global__ void prep_xb(const float* __restrict__ x, const float* __restrict__ dinv,
                        ushort* __restrict__ xb, int N) {
    int i = blockIdx.x * blockDim.x + threadIdx.x;
    if (i >= N * 16) return;
    int n = i >> 4, k = i & 15;
    xb[i] = (k < 9) ? f2b(x[n * 9 + k] * dinv[n]) : (ushort)0;
}

// ---------------- conv1 fused: agg = dinv_i*(sum xb[src] + xb[i]); out = relu(agg@W1+b1)
__global__ void conv1_fused(const ushort* __restrict__ xb, const float* __restrict__ dinv,
                            const int* __restrict__ rowstart,
                            const int* __restrict__ col, const float* __restrict__ W1,
                            const float* __restrict__ b1, float* __restrict__ out, int N) {
    int gtid = blockIdx.x * blockDim.x + threadIdx.x;
    int i = __builtin_amdgcn_readfirstlane(gtid >> 6);
    int lane = threadIdx.x & 63;
    int f16 = lane & 15, grp = lane >> 4;
    if (i >= N) return;
    float di = dinv[i];
    float sv = b2f(xb[(size_t)i * 16 + f16]);   // self (already dinv_i-scaled)
    float acc = 0.f;
    int s = rowstart[i], e = rowstart[i + 1];
    for (int base = s; base < e; base += 64) {
        int cnt = e - base;
        if (cnt > 64) cnt = 64;
        int idx = 0;
        if (lane < cnt) idx = col[base + lane];
        for (int j = 0; j < cnt; j += 8) {
            int j0 = j + grp, j1 = j + 4 + grp;
            int s0 = __shfl(idx, j0);
            int s1 = __shfl(idx, j1 & 63);
            float v0 = (j0 < cnt) ? b2f(xb[(size_t)s0 * 16 + f16]) : 0.f;
            float v1 = (j1 < cnt) ? b2f(xb[(size_t)s1 * 16 + f16]) : 0.f;
            acc += v0 + v1;
        }
    }
    // reduce 4 edge-groups
    acc += __shfl_xor(acc, 16);
    acc += __shfl_xor(acc, 32);
    float aggf = di * (acc + sv);            // lane k (k<9) holds agg[k]

    float o = b1[lane];
#pragma unroll
    for (int k = 0; k < 9; ++k) {
        float ak = __shfl(aggf, k);
        o = fmaf(ak, W1[k * H + lane], o);
    }
    out[(size_t)i * H + lane] = fmaxf(o, 0.f);
}

// ---------------- linear: N x 64 @ 64 x 64 (16 nodes/block), scaled, bf16 out ----------------
__global__ void lin_h(const float* __restrict__ h, const float* __restrict__ W,
                      const float* __restrict__ dinv, ushort* __restrict__ out, int N) {
    __shared__ float Ws[H * H];     // 16 KB
    __shared__ float hs[16 * H];    // 4 KB
    int tid = threadIdx.x;
    int node0 = blockIdx.x * 16;
    for (int idx = tid; idx < H * H; idx += 256) Ws[idx] = W[idx];
    for (int idx = tid; idx < 16 * H; idx += 256) {
        int n = node0 + (idx >> 6);
        hs[idx] = (n < N) ? h[n * H + (idx & 63)] : 0.f;
    }
    __syncthreads();
    int nlb = tid >> 6, f = tid & 63;
    float a0 = 0.f, a1 = 0.f, a2 = 0.f, a3 = 0.f;
#pragma unroll 8
    for (int k = 0; k < H; ++k) {
        float w = Ws[k * H + f];
        a0 += hs[(nlb) * H + k] * w;
        a1 += hs[(nlb + 4) * H + k] * w;
        a2 += hs[(nlb + 8) * H + k] * w;
        a3 += hs[(nlb + 12) * H + k] * w;
    }
    int n;
    n = node0 + nlb;      if (n < N) out[n * H + f] = f2b(a0 * dinv[n]);
    n = node0 + nlb + 4;  if (n < N) out[n * H + f] = f2b(a1 * dinv[n]);
    n = node0 + nlb + 8;  if (n < N) out[n * H + f] = f2b(a2 * dinv[n]);
    n = node0 + nlb + 12; if (n < N) out[n * H + f] = f2b(a3 * dinv[n]);
}

// ---------------- aggregate (bf16 gather, scalarized indices) ----------------
__global__ void aggregate_b(const ushort* __restrict__ hb, const float* __restrict__ dinv,
                            const int* __restrict__ rowstart,
                            const int* __restrict__ col, const float* __restrict__ bias,
                            float* __restrict__ out, int N) {
    int gtid = blockIdx.x * blockDim.x + threadIdx.x;
    int i = __builtin_amdgcn_readfirstlane(gtid >> 6);   // node = wave (uniform, SGPR)
    int f = threadIdx.x & 63;
    if (i >= N) return;
    float acc = b2f(hb[(size_t)i * H + f]);  // self-loop term (dinv_i*hw[i])
    int s = rowstart[i], e = rowstart[i + 1];
    int p = s;
    for (; p + 8 <= e; p += 8) {
        int i0 = __builtin_amdgcn_readfirstlane(col[p + 0]);
        int i1 = __builtin_amdgcn_readfirstlane(col[p + 1]);
        int i2 = __builtin_amdgcn_readfirstlane(col[p + 2]);
        int i3 = __builtin_amdgcn_readfirstlane(col[p + 3]);
        int i4 = __builtin_amdgcn_readfirstlane(col[p + 4]);
        int i5 = __builtin_amdgcn_readfirstlane(col[p + 5]);
        int i6 = __builtin_amdgcn_readfirstlane(col[p + 6]);
        int i7 = __builtin_amdgcn_readfirstlane(col[p + 7]);
        float v0 = b2f(hb[(size_t)i0 * H + f]);
        float v1 = b2f(hb[(size_t)i1 * H + f]);
        float v2 = b2f(hb[(size_t)i2 * H + f]);
        float v3 = b2f(hb[(size_t)i3 * H + f]);
        float v4 = b2f(hb[(size_t)i4 * H + f]);
        float v5 = b2f(hb[(size_t)i5 * H + f]);
        float v6 = b2f(hb[(size_t)i6 * H + f]);
        float v7 = b2f(hb[(size_t)i7 * H + f]);
        acc += ((v0 + v1) + (v2 + v3)) + ((v4 + v5) + (v6 + v7));
    }
    for (; p < e; ++p) {
        int s0 = __builtin_amdgcn_readfirstlane(col[p]);
        acc += b2f(hb[(size_t)s0 * H + f]);
    }
    out[(size_t)i * H + f] = fmaxf(bias[f] + dinv[i] * acc, 0.f);
}

// ---------------- final MLP: one wave per graph, shfl-based ----------------
__global__ void mlp(const float* __restrict__ pooled, const float* __restrict__ u,
                    const float* __restrict__ A1, const float* __restrict__ c1,
                    const float* __restrict__ A2, const float* __restrict__ c2,
                    const float* __restrict__ A3, const float* __restrict__ c3,
                    const float* __restrict__ A4, const float* __restrict__ c4,
                    const float* __restrict__ A5, const float* __restrict__ c5,
                    float* __restrict__ out, int G) {
    int wid = (blockIdx.x * blockDim.x + threadIdx.x) >> 6;  // wave = graph
    int lane = threadIdx.x & 63;
    if (wid >= G) return;
    int g = wid;

    float zreg = pooled[g * H + lane];
    float u0 = u[g * 4 + 0], u1 = u[g * 4 + 1], u2 = u[g * 4 + 2], u3 = u[g * 4 + 3];

    // layer 1: 68 -> 50
    float acc = (lane < 50) ? c1[lane] : 0.f;
#pragma unroll
    for (int k = 0; k < 64; ++k) {
        float zk = __shfl(zreg, k);
        float w = (lane < 50) ? A1[k * 50 + lane] : 0.f;
        acc = fmaf(zk, w, acc);
    }
    {
        float w;
        w = (lane < 50) ? A1[64 * 50 + lane] : 0.f; acc = fmaf(u0, w, acc);
        w = (lane < 50) ? A1[65 * 50 + lane] : 0.f; acc = fmaf(u1, w, acc);
        w = (lane < 50) ? A1[66 * 50 + lane] : 0.f; acc = fmaf(u2, w, acc);
        w = (lane < 50) ? A1[67 * 50 + lane] : 0.f; acc = fmaf(u3, w, acc);
    }
    float z1v = fmaxf(acc, 0.f);

    // layer 2: 50 -> 30
    acc = (lane < 30) ? c2[lane] : 0.f;
#pragma unroll
    for (int k = 0; k < 50; ++k) {
        float zk = __shfl(z1v, k);
        float w = (lane < 30) ? A2[k * 30 + lane] : 0.f;
        acc = fmaf(zk, w, acc);
    }
    float z2v = fmaxf(acc, 0.f);

    // layer 3: 30 -> 20
    acc = (lane < 20) ? c3[lane] : 0.f;
#pragma unroll
    for (int k = 0; k < 30; ++k) {
        float zk = __shfl(z2v, k);
        float w = (lane < 20) ? A3[k * 20 + lane] : 0.f;
        acc = fmaf(zk, w, acc);
    }
    float z3v = fmaxf(acc, 0.f);

    // layer 4: 20 -> 5
    acc = (lane < 5) ? c4[lane] : 0.f;
#pragma unroll
    for (int k = 0; k < 20; ++k) {
        float zk = __shfl(z3v, k);
        float w = (lane < 5) ? A4[k * 5 + lane] : 0.f;
        acc = fmaf(zk, w, acc);
    }
    float z4v = fmaxf(acc, 0.f);

    // layer 5: 5 -> 1
    acc = c5[0];
#pragma unroll
    for (int k = 0; k < 5; ++k) {
        float zk = __shfl(z4v, k);
        acc = fmaf(zk, A5[k], acc);
    }
    if (lane == 0) out[g] = fmaxf(acc, 0.f);
}

extern "C" void kernel_launch(void* const* d_in, const int* in_sizes, int n_in,
                              void* d_out, int out_size, void* d_ws, size_t ws_size,
                              hipStream_t stream) {
    const float* x     = (const float*)d_in[0];
    const int*   edge  = (const int*)d_in[1];
    const int*   batch = (const int*)d_in[2];
    const float* u     = (const float*)d_in[3];
    const float* W1 = (const float*)d_in[4];  const float* b1 = (const float*)d_in[5];
    const float* W2 = (const float*)d_in[6];  const float* b2 = (const float*)d_in[7];
    const float* W3 = (const float*)d_in[8];  const float* b3 = (const float*)d_in[9];
    const float* A1 = (const float*)d_in[10]; const float* c1 = (const float*)d_in[11];
    const float* A2 = (const float*)d_in[12]; const float* c2 = (const float*)d_in[13];
    const float* A3 = (const float*)d_in[14]; const float* c3 = (const float*)d_in[15];
    const float* A4 = (const float*)d_in[16]; const float* c4 = (const float*)d_in[17];
    const float* A5 = (const float*)d_in[18]; const float* c5 = (const float*)d_in[19];

    const int N = in_sizes[2];          // 100000
    const int E = in_sizes[1] / 2;      // 3200000
    const int G = in_sizes[3] / 4;      // 256
    const int* src = edge;
    const int* dst = edge + E;
    const int nbuck = (N + BNODES - 1) >> BNODE_SHIFT;   // 391

    // ---- workspace layout (pairs4 aliases hb region: pairs4 dead before lin_h writes) ----
    char* ws = (char*)d_ws;
    size_t off = 0;
    auto alloc = [&](size_t bytes) -> void* {
        void* p = ws + off;
        off = (off + bytes + 255) & ~(size_t)255;
        return p;
    };
    ushort* hb       = (ushort*)alloc((size_t)N * H * 2);  // bf16 gather operand; aliases pairs4
    float*  h        = (float*)alloc((size_t)N * H * 4);
    int*    col      = (int*)alloc((size_t)E * 4);
    ushort* xb       = (ushort*)alloc((size_t)N * 16 * 2);
    int*    rowstart = (int*)alloc((size_t)(N + 1) * 4);
    float*  dinv     = (float*)alloc((size_t)N * 4);
    int*    bcounts  = (int*)alloc((size_t)nbuck * 4);
    int*    boff     = (int*)alloc((size_t)(nbuck + 1) * 4);
    int*    bcur     = (int*)alloc((size_t)nbuck * 64);    // 64B-padded cursors
    int*    nodestart= (int*)alloc((size_t)(G + 1) * 4);
    float*  pooled   = (float*)alloc((size_t)G * H * 4);
    int*    pairs4   = (int*)hb;

    const int nbN   = (N + 255) / 256;
    const int nbAgg = (N + 3) / 4;       // 4 waves/block, wave per node
    const int nchunks = (E + CHUNK - 1) / CHUNK;   // 782

    // ---- CSR build via block-local LDS sort ----
    zero_i32<<<(nbuck + 255) / 256, 256, 0, stream>>>(bcounts, nbuck);
    bucket_hist<<<256, 256, 0, stream>>>(dst, E, bcounts, nbuck);
    bucket_scan<<<1, 1024, 0, stream>>>(bcounts, boff, bcur, rowstart, nbuck, E, N);
    edge_sort_scatter<<<nchunks, 256, 0, stream>>>(src, dst, E, nbuck, bcur, pairs4);
    bucket_build<<<nbuck, 256, 0, stream>>>(pairs4, boff, col, rowstart, dinv, N);
    graph_bounds<<<nbN, 256, 0, stream>>>(batch, nodestart, N, G);

    // ---- conv1 (fused: aggregate 9-wide raw bf16 x, then W1) ----
    prep_xb<<<(N * 16 + 255) / 256, 256, 0, stream>>>(x, dinv, xb, N);
    conv1_fused<<<nbAgg, 256, 0, stream>>>(xb, dinv, rowstart, col, W1, b1, h, N);
    // ---- conv2 ----
    lin_h<<<(N + 15) / 16, 256, 0, stream>>>(h, W2, dinv, hb, N);
    aggregate_b<<<nbAgg, 256, 0, stream>>>(hb, dinv, rowstart, col, b2, h, N);
    // ---- conv3 ----
    lin_h<<<(N + 15) / 16, 256, 0, stream>>>(h, W3, dinv, hb, N);
    aggregate_b<<<nbAgg, 256, 0, stream>>>(hb, dinv, rowstart, col, b3, h, N);

    // ---- mean pool + final MLP ----
    pool_mean<<<G, 256, 0, stream>>>(h, nodestart, pooled, G);
    mlp<<<(G * 64 + 255) / 256, 256, 0, stream>>>(pooled, u, A1, c1, A2, c2, A3, c3,
                                                  A4, c4, A5, c5, (float*)d_out, G);
}